// Round 1
// baseline (9310.694 us; speedup 1.0000x reference)
//
#include <hip/hip_runtime.h>

#define PI2 6.28318530717958647692f

__device__ __forceinline__ void cfma(float2& acc, float2 a, float2 b) {
  acc.x += a.x * b.x - a.y * b.y;
  acc.y += a.x * b.y + a.y * b.x;
}

__device__ __forceinline__ float2 twf(int m, float invN, float sign) {
  float a = sign * PI2 * (float)m * invN;
  float s, c;
  __sincosf(a, &s, &c);
  return make_float2(c, s);
}

// ---------------- spectral forward ----------------
// x: [b][c][t][xx][y][z], rows = b*c*t*xx*y, out A: [row][zk(4)]
__global__ void k_fwd_z(const float* __restrict__ x, float2* __restrict__ out, int nrows) {
  int r = blockIdx.x * 256 + threadIdx.x;
  if (r >= nrows) return;
  const float* p = x + (size_t)r * 16;
  float v[16];
#pragma unroll
  for (int z = 0; z < 16; z++) v[z] = p[z];
#pragma unroll
  for (int zk = 0; zk < 4; zk++) {
    float re = 0.f, im = 0.f;
#pragma unroll
    for (int z = 0; z < 16; z++) {
      float2 t = twf((z * zk) & 15, 1.f / 16.f, -1.f);
      re += v[z] * t.x;
      im += v[z] * t.y;
    }
    out[(size_t)r * 4 + zk] = make_float2(re, im);
  }
}

// in A: [slab(b,c,t,xx)][y(32)][zk(4)] -> out Bb: [slab][yk(8)][zk(4)]
__global__ void k_fwd_y(const float2* __restrict__ in, float2* __restrict__ out, int n) {
  int i = blockIdx.x * 256 + threadIdx.x;
  if (i >= n) return;
  int zk = i & 3, yk = (i >> 2) & 7, slab = i >> 5;
  const float2* p = in + (size_t)slab * 128 + zk;
  float2 acc = make_float2(0.f, 0.f);
  for (int y = 0; y < 32; y++) cfma(acc, p[y * 4], twf((y * yk) & 31, 1.f / 32.f, -1.f));
  out[i] = acc;
}

// in Bb: [slab3(b,c,t)][xx(32)][yk][zk] -> out Cb: [slab3][xi(16)][yk][zk]
__global__ void k_fwd_x(const float2* __restrict__ in, float2* __restrict__ out, int n) {
  int i = blockIdx.x * 256 + threadIdx.x;
  if (i >= n) return;
  int zk = i & 3, yk = (i >> 2) & 7, xi = (i >> 5) & 15, slab = i >> 9;
  int xk = (xi < 8) ? xi : xi + 16;
  const float2* p = in + (size_t)slab * 1024 + yk * 4 + zk;
  float2 acc = make_float2(0.f, 0.f);
  for (int xx = 0; xx < 32; xx++) cfma(acc, p[xx * 32], twf((xx * xk) & 31, 1.f / 32.f, -1.f));
  out[i] = acc;
}

// in Cb: [bc][t(16)][xi][yk][zk] -> out D: [bc][ti(8)][xi][yk][zk]
__global__ void k_fwd_t(const float2* __restrict__ in, float2* __restrict__ out, int n) {
  int i = blockIdx.x * 256 + threadIdx.x;
  if (i >= n) return;
  int zk = i & 3, yk = (i >> 2) & 7, xi = (i >> 5) & 15, ti = (i >> 9) & 7, bc = i >> 12;
  int tk = (ti < 4) ? ti : ti + 8;
  const float2* p = in + (size_t)bc * 8192 + xi * 32 + yk * 4 + zk;
  float2 acc = make_float2(0.f, 0.f);
  for (int t = 0; t < 16; t++) cfma(acc, p[t * 512], twf((t * tk) & 15, 1.f / 16.f, -1.f));
  out[i] = acc;
}

// in D: [b][c(20)][mode(4096)] -> out E: [b][ck][mode]
__global__ void k_fwd_c(const float2* __restrict__ in, float2* __restrict__ out, int n) {
  int i = blockIdx.x * 256 + threadIdx.x;
  if (i >= n) return;
  int mode = i & 4095, r = i >> 12, ck = r % 20, b = r / 20;
  const float2* p = in + (size_t)b * 81920 + mode;
  float2 acc = make_float2(0.f, 0.f);
  for (int c = 0; c < 20; c++) cfma(acc, p[(size_t)c * 4096], twf((c * ck) % 20, 1.f / 20.f, -1.f));
  out[i] = acc;
}

// in E: [b(4)][ck][mode] -> out F: [bk][ck][mode]
__global__ void k_fwd_b(const float2* __restrict__ in, float2* __restrict__ out, int n) {
  int i = blockIdx.x * 256 + threadIdx.x;
  if (i >= n) return;
  int mode = i & 4095, r = i >> 12, ck = r % 20, bk = r / 20;
  const float2* p = in + (size_t)ck * 4096 + mode;
  float2 acc = make_float2(0.f, 0.f);
  for (int b = 0; b < 4; b++) cfma(acc, p[(size_t)b * 81920], twf((b * bk) & 3, 0.25f, -1.f));
  out[i] = acc;
}

// spectral channel mix: out G[bk][o][mode] = sum_i F[bk][i][mode] * W_corner[i][o][mode-local]
__global__ void k_smul(const float2* __restrict__ in,
                       const float* __restrict__ sw1, const float* __restrict__ sw2,
                       const float* __restrict__ sw3, const float* __restrict__ sw4,
                       float2* __restrict__ out, int n) {
  int i = blockIdx.x * 256 + threadIdx.x;
  if (i >= n) return;
  int mode = i & 4095, r = i >> 12, o = r % 20, bk = r / 20;
  int ti = mode >> 9, xi = (mode >> 5) & 15, yk = (mode >> 2) & 7, zk = mode & 3;
  const float* w = (ti < 4) ? ((xi < 8) ? sw1 : sw3) : ((xi < 8) ? sw2 : sw4);
  int tl = ti & 3, xl = xi & 7;
  const float2* wp = (const float2*)w;
  const float2* ip = in + (size_t)bk * 81920 + mode;
  size_t wsub = (size_t)o * 1024 + (size_t)tl * 256 + (size_t)xl * 32 + yk * 4 + zk;
  float2 acc = make_float2(0.f, 0.f);
  for (int ci = 0; ci < 20; ci++) cfma(acc, ip[(size_t)ci * 4096], wp[(size_t)ci * 20480 + wsub]);
  out[i] = acc;
}

// ---------------- spectral inverse ----------------
// in G: [bc][ti(8)][xi][yk][zk] -> out: [bc][tp(16)][xi][yk][zk]
__global__ void k_inv_t(const float2* __restrict__ in, float2* __restrict__ out, int n) {
  int i = blockIdx.x * 256 + threadIdx.x;
  if (i >= n) return;
  int zk = i & 3, yk = (i >> 2) & 7, xi = (i >> 5) & 15, tp = (i >> 9) & 15, bc = i >> 13;
  const float2* p = in + (size_t)bc * 4096 + xi * 32 + yk * 4 + zk;
  float2 acc = make_float2(0.f, 0.f);
  for (int ti = 0; ti < 8; ti++) {
    int tk = (ti < 4) ? ti : ti + 8;
    cfma(acc, p[ti * 512], twf((tk * tp) & 15, 1.f / 16.f, 1.f));
  }
  out[i] = acc;
}

// in: [bc][tp(16)][xi(16)][yk][zk] -> out: [bc][tp][xp(32)][yk][zk]
__global__ void k_inv_x(const float2* __restrict__ in, float2* __restrict__ out, int n) {
  int i = blockIdx.x * 256 + threadIdx.x;
  if (i >= n) return;
  int zk = i & 3, yk = (i >> 2) & 7, xp = (i >> 5) & 31, tp = (i >> 10) & 15, bc = i >> 14;
  const float2* p = in + (size_t)bc * 8192 + tp * 512 + yk * 4 + zk;
  float2 acc = make_float2(0.f, 0.f);
  for (int xi = 0; xi < 16; xi++) {
    int xk = (xi < 8) ? xi : xi + 16;
    cfma(acc, p[xi * 32], twf((xk * xp) & 31, 1.f / 32.f, 1.f));
  }
  out[i] = acc;
}

// in: [bc][tp][xp][yk(8)][zk] -> out: [bc][tp][xp][yp(32)][zk]
__global__ void k_inv_y(const float2* __restrict__ in, float2* __restrict__ out, int n) {
  int i = blockIdx.x * 256 + threadIdx.x;
  if (i >= n) return;
  int zk = i & 3, yp = (i >> 2) & 31, xp = (i >> 7) & 31, tp = (i >> 12) & 15, bc = i >> 16;
  const float2* p = in + (size_t)bc * 16384 + tp * 1024 + xp * 32 + zk;
  float2 acc = make_float2(0.f, 0.f);
  for (int yk = 0; yk < 8; yk++) cfma(acc, p[yk * 4], twf((yk * yp) & 31, 1.f / 32.f, 1.f));
  out[i] = acc;
}

// c2r along z: pocketfft semantics (imag of bin 0 dropped; bins 4..8 zero).
__global__ void k_inv_z(const float2* __restrict__ in, float* __restrict__ out, int n) {
  int i = blockIdx.x * 256 + threadIdx.x;
  if (i >= n) return;
  int zp = i & 15, row = i >> 4;
  const float2* p = in + (size_t)row * 4;
  float val = p[0].x;
#pragma unroll
  for (int zk = 1; zk < 4; zk++) {
    float2 t = twf((zk * zp) & 15, 1.f / 16.f, 1.f);
    val += 2.f * (p[zk].x * t.x - p[zk].y * t.y);
  }
  out[i] = val * (1.f / 262144.f);
}

// ---------------- pointwise path (adds into d_out) ----------------
__global__ void k_x2(const float* __restrict__ x, const float* __restrict__ w,
                     const float* __restrict__ bias, float* __restrict__ out, int n) {
  int i = blockIdx.x * 256 + threadIdx.x;
  if (i >= n) return;
  int s = i & 262143, b = i >> 18;
  float xv[20];
#pragma unroll
  for (int c = 0; c < 20; c++) xv[c] = x[((size_t)b * 20 + c) * 262144 + s];
#pragma unroll
  for (int o = 0; o < 20; o++) {
    float a = bias[o];
#pragma unroll
    for (int c = 0; c < 20; c++) a += w[o * 20 + c] * xv[c];
    out[((size_t)b * 20 + o) * 262144 + s] += a;
  }
}

// ---------------- U-Net: convs ----------------
// one thread per output position, 20 out-channel accumulators; W: [o][ci][81]
__global__ void k_conv4d_pos(const float* __restrict__ in1, int Ci1,
                             const float* __restrict__ in2, int Ci2,
                             const float* __restrict__ W, float* __restrict__ out,
                             int Ti, int Xi, int Yi, int Zi,
                             int To, int Xo, int Yo, int Zo, int stride, int n) {
  int idx = blockIdx.x * 256 + threadIdx.x;
  if (idx >= n) return;
  int zo = idx % Zo; int r = idx / Zo;
  int yo = r % Yo; r /= Yo;
  int xo = r % Xo; r /= Xo;
  int to = r % To; int b = r / To;
  float acc[20];
#pragma unroll
  for (int o = 0; o < 20; o++) acc[o] = 0.f;
  int Ci = Ci1 + Ci2;
  size_t in_sp = (size_t)Ti * Xi * Yi * Zi;
  for (int ci = 0; ci < Ci; ci++) {
    const float* base = (ci < Ci1) ? in1 + ((size_t)b * Ci1 + ci) * in_sp
                                   : in2 + ((size_t)b * Ci2 + (ci - Ci1)) * in_sp;
    const float* wc = W + (size_t)ci * 81;
    for (int kt = 0; kt < 3; kt++) {
      int t = to * stride + kt - 1; if (t < 0 || t >= Ti) continue;
      for (int kx = 0; kx < 3; kx++) {
        int xx = xo * stride + kx - 1; if (xx < 0 || xx >= Xi) continue;
        for (int ky = 0; ky < 3; ky++) {
          int y = yo * stride + ky - 1; if (y < 0 || y >= Yi) continue;
          for (int kz = 0; kz < 3; kz++) {
            int z = zo * stride + kz - 1; if (z < 0 || z >= Zi) continue;
            float v = base[(((size_t)t * Xi + xx) * Yi + y) * Zi + z];
            int tap = ((kt * 3 + kx) * 3 + ky) * 3 + kz;
#pragma unroll
            for (int o = 0; o < 20; o++) acc[o] += v * wc[(size_t)o * Ci * 81 + tap];
          }
        }
      }
    }
  }
  size_t osp = (size_t)To * Xo * Yo * Zo;
  size_t obase = (size_t)b * 20 * osp + (((size_t)to * Xo + xo) * Yo + yo) * Zo + zo;
#pragma unroll
  for (int o = 0; o < 20; o++) out[obase + (size_t)o * osp] = acc[o];
}

// one thread per output element (small layers); W: [o][ci][81]
__global__ void k_conv4d_elem(const float* __restrict__ in, const float* __restrict__ W,
                              float* __restrict__ out, int Ci,
                              int Ti, int Xi, int Yi, int Zi,
                              int To, int Xo, int Yo, int Zo, int stride, int n) {
  int idx = blockIdx.x * 256 + threadIdx.x;
  if (idx >= n) return;
  int zo = idx % Zo; int r = idx / Zo;
  int yo = r % Yo; r /= Yo;
  int xo = r % Xo; r /= Xo;
  int to = r % To; r /= To;
  int o = r % 20; int b = r / 20;
  float acc = 0.f;
  size_t in_sp = (size_t)Ti * Xi * Yi * Zi;
  for (int ci = 0; ci < Ci; ci++) {
    const float* base = in + ((size_t)b * Ci + ci) * in_sp;
    const float* wc = W + ((size_t)o * Ci + ci) * 81;
    for (int kt = 0; kt < 3; kt++) {
      int t = to * stride + kt - 1; if (t < 0 || t >= Ti) continue;
      for (int kx = 0; kx < 3; kx++) {
        int xx = xo * stride + kx - 1; if (xx < 0 || xx >= Xi) continue;
        for (int ky = 0; ky < 3; ky++) {
          int y = yo * stride + ky - 1; if (y < 0 || y >= Yi) continue;
          for (int kz = 0; kz < 3; kz++) {
            int z = zo * stride + kz - 1; if (z < 0 || z >= Zi) continue;
            acc += base[(((size_t)t * Xi + xx) * Yi + y) * Zi + z] * wc[((kt * 3 + kx) * 3 + ky) * 3 + kz];
          }
        }
      }
    }
  }
  out[idx] = acc;
}

// final conv: concat(x, od0), +bias, +accumulator already in d_out, relu; dims fixed
__global__ void k_conv4d_final(const float* __restrict__ in1, const float* __restrict__ in2,
                               const float* __restrict__ W, const float* __restrict__ bias,
                               float* __restrict__ io, int n) {
  int idx = blockIdx.x * 256 + threadIdx.x;
  if (idx >= n) return;
  int zo = idx & 15; int r = idx >> 4;
  int yo = r & 31; r >>= 5;
  int xo = r & 31; r >>= 5;
  int to = r & 15; int b = r >> 4;
  float acc[20];
#pragma unroll
  for (int o = 0; o < 20; o++) acc[o] = 0.f;
  for (int ci = 0; ci < 40; ci++) {
    const float* base = (ci < 20) ? in1 + ((size_t)b * 20 + ci) * 262144
                                  : in2 + ((size_t)b * 20 + (ci - 20)) * 262144;
    for (int kt = 0; kt < 3; kt++) {
      int t = to + kt - 1; if (t < 0 || t >= 16) continue;
      for (int kx = 0; kx < 3; kx++) {
        int xx = xo + kx - 1; if (xx < 0 || xx >= 32) continue;
        for (int ky = 0; ky < 3; ky++) {
          int y = yo + ky - 1; if (y < 0 || y >= 32) continue;
          for (int kz = 0; kz < 3; kz++) {
            int z = zo + kz - 1; if (z < 0 || z >= 16) continue;
            float v = base[(((size_t)t * 32 + xx) * 32 + y) * 16 + z];
            int tap = ((kt * 3 + kx) * 3 + ky) * 3 + kz;
#pragma unroll
            for (int o = 0; o < 20; o++) acc[o] += v * W[((size_t)o * 40 + ci) * 81 + tap];
          }
        }
      }
    }
  }
  size_t obase = (size_t)b * 20 * 262144 + (((size_t)to * 32 + xo) * 32 + yo) * 16 + zo;
#pragma unroll
  for (int o = 0; o < 20; o++) {
    float v2 = acc[o] + bias[o] + io[obase + (size_t)o * 262144];
    io[obase + (size_t)o * 262144] = fmaxf(v2, 0.f);
  }
}

// ---------------- BN ----------------
__global__ void k_bn_stats(const float* __restrict__ d, int S, float* __restrict__ stats) {
  int c = blockIdx.x;
  int tid = threadIdx.x;
  float s = 0.f, s2 = 0.f;
  for (int b = 0; b < 4; b++) {
    const float* p = d + ((size_t)b * 20 + c) * S;
    for (int i = tid; i < S; i += 256) { float v = p[i]; s += v; s2 += v * v; }
  }
  __shared__ float ls[256], lq[256];
  ls[tid] = s; lq[tid] = s2;
  __syncthreads();
  for (int off = 128; off > 0; off >>= 1) {
    if (tid < off) { ls[tid] += ls[tid + off]; lq[tid] += lq[tid + off]; }
    __syncthreads();
  }
  if (tid == 0) {
    float cnt = 4.f * (float)S;
    float mean = ls[0] / cnt;
    float var = lq[0] / cnt - mean * mean;
    stats[2 * c] = mean;
    stats[2 * c + 1] = rsqrtf(var + 1e-5f);
  }
}

__global__ void k_bn_apply(float* __restrict__ d, int S, const float* __restrict__ stats,
                           const float* __restrict__ g, const float* __restrict__ bb, int n) {
  int idx = blockIdx.x * 256 + threadIdx.x;
  if (idx >= n) return;
  int c = (idx / S) % 20;
  float v = d[idx];
  v = (v - stats[2 * c]) * stats[2 * c + 1] * g[c] + bb[c];
  d[idx] = (v >= 0.f) ? v : 0.1f * v;
}

// ---------------- deconv (ConvTranspose4d k=4 s=2 p=1), bias+lrelu fused ----------------
__device__ __forceinline__ int dcands(int p, int n_in, int* q, int* k) {
  int cnt = 0;
  int q0 = (p + 1) >> 1, k0 = p + 1 - 2 * q0;
  if (q0 >= 0 && q0 < n_in) { q[cnt] = q0; k[cnt] = k0; cnt++; }
  int q1 = q0 - 1, k1 = k0 + 2;
  if (q1 >= 0 && q1 < n_in) { q[cnt] = q1; k[cnt] = k1; cnt++; }
  return cnt;
}

__global__ void k_deconv4d(const float* __restrict__ in1, int Ci1,
                           const float* __restrict__ in2, int Ci2,
                           const float* __restrict__ W, const float* __restrict__ bias,
                           float* __restrict__ out,
                           int Ti, int Xi, int Yi, int Zi, int n) {
  int idx = blockIdx.x * 256 + threadIdx.x;
  if (idx >= n) return;
  int To = 2 * Ti, Xo = 2 * Xi, Yo = 2 * Yi, Zo = 2 * Zi;
  int zo = idx % Zo; int r = idx / Zo;
  int yo = r % Yo; r /= Yo;
  int xo = r % Xo; r /= Xo;
  int to = r % To; int b = r / To;
  int qt[2], kt[2], qx[2], kx[2], qy[2], ky[2], qz[2], kz[2];
  int nt = dcands(to, Ti, qt, kt), nx = dcands(xo, Xi, qx, kx);
  int ny = dcands(yo, Yi, qy, ky), nz = dcands(zo, Zi, qz, kz);
  float acc[20];
#pragma unroll
  for (int o = 0; o < 20; o++) acc[o] = 0.f;
  int Ci = Ci1 + Ci2;
  size_t in_sp = (size_t)Ti * Xi * Yi * Zi;
  for (int ci = 0; ci < Ci; ci++) {
    const float* base = (ci < Ci1) ? in1 + ((size_t)b * Ci1 + ci) * in_sp
                                   : in2 + ((size_t)b * Ci2 + (ci - Ci1)) * in_sp;
    const float* wc = W + (size_t)ci * 5120;  // [ci][o(20)][256]
    for (int it = 0; it < nt; it++)
      for (int ix = 0; ix < nx; ix++)
        for (int iy = 0; iy < ny; iy++)
          for (int iz = 0; iz < nz; iz++) {
            float v = base[(((size_t)qt[it] * Xi + qx[ix]) * Yi + qy[iy]) * Zi + qz[iz]];
            int tap = ((kt[it] * 4 + kx[ix]) * 4 + ky[iy]) * 4 + kz[iz];
#pragma unroll
            for (int o = 0; o < 20; o++) acc[o] += v * wc[o * 256 + tap];
          }
  }
  size_t osp = (size_t)To * Xo * Yo * Zo;
  size_t obase = (size_t)b * 20 * osp + (((size_t)to * Xo + xo) * Yo + yo) * Zo + zo;
#pragma unroll
  for (int o = 0; o < 20; o++) {
    float v2 = acc[o] + bias[o];
    out[obase + (size_t)o * osp] = (v2 >= 0.f) ? v2 : 0.1f * v2;
  }
}

extern "C" void kernel_launch(void* const* d_in, const int* in_sizes, int n_in,
                              void* d_out, int out_size, void* d_ws, size_t ws_size,
                              hipStream_t stream) {
  const float* x     = (const float*)d_in[0];
  const float* sw1   = (const float*)d_in[1];
  const float* sw2   = (const float*)d_in[2];
  const float* sw3   = (const float*)d_in[3];
  const float* sw4   = (const float*)d_in[4];
  const float* w_pw  = (const float*)d_in[5];
  const float* b_pw  = (const float*)d_in[6];
  const float* c1_w  = (const float*)d_in[7];
  const float* c2_w  = (const float*)d_in[8];
  const float* c21_w = (const float*)d_in[9];
  const float* c3_w  = (const float*)d_in[10];
  const float* c31_w = (const float*)d_in[11];
  const float* bn1_g = (const float*)d_in[12];
  const float* bn1_b = (const float*)d_in[13];
  const float* bn2_g = (const float*)d_in[14];
  const float* bn2_b = (const float*)d_in[15];
  const float* bn21_g = (const float*)d_in[16];
  const float* bn21_b = (const float*)d_in[17];
  const float* bn3_g = (const float*)d_in[18];
  const float* bn3_b = (const float*)d_in[19];
  const float* bn31_g = (const float*)d_in[20];
  const float* bn31_b = (const float*)d_in[21];
  const float* d2_w  = (const float*)d_in[22];
  const float* d2_b  = (const float*)d_in[23];
  const float* d1_w  = (const float*)d_in[24];
  const float* d1_b  = (const float*)d_in[25];
  const float* d0_w  = (const float*)d_in[26];
  const float* d0_b  = (const float*)d_in[27];
  const float* out_w = (const float*)d_in[28];
  const float* out_b = (const float*)d_in[29];
  float* out = (float*)d_out;
  float* ws = (float*)d_ws;

  // spectral arena (used first, then overlaid by the U-Net arena — stream-ordered)
  float2* A  = (float2*)(ws);             // 5,242,880 c
  float2* Bb = (float2*)(ws + 10485760);  // 1,310,720 c
  float2* Cb = (float2*)(ws + 13107200);  //   655,360 c
  float2* Dd = (float2*)(ws + 14417920);  //   327,680 c
  float2* Ee = (float2*)(ws + 15073280);  //   327,680 c
  float2* Ff = (float2*)(ws + 15728640);  //   327,680 c
  float2* Gg = (float2*)(ws + 16384000);  //   327,680 c

  // U-Net arena (overlays spectral arena from offset 0)
  float* oc1   = ws;             // 1,310,720
  float* oc2a  = ws + 1310720;   //    81,920
  float* oc2   = ws + 1392640;   //    81,920
  float* oc3a  = ws + 1474560;   //     5,120
  float* oc3   = ws + 1479680;   //     5,120
  float* od2   = ws + 1484800;   //    81,920
  float* od1   = ws + 1566720;   // 1,310,720
  float* od0   = ws + 2877440;   // 20,971,520
  float* stats = ws + 23848960;  //        40

  auto nb = [](int n) { return (n + 255) / 256; };
  dim3 blk(256);

  // ---- spectral path: x1 -> d_out ----
  k_fwd_z<<<nb(1310720), blk, 0, stream>>>(x, A, 1310720);
  k_fwd_y<<<nb(1310720), blk, 0, stream>>>(A, Bb, 1310720);
  k_fwd_x<<<nb(655360), blk, 0, stream>>>(Bb, Cb, 655360);
  k_fwd_t<<<nb(327680), blk, 0, stream>>>(Cb, Dd, 327680);
  k_fwd_c<<<nb(327680), blk, 0, stream>>>(Dd, Ee, 327680);
  k_fwd_b<<<nb(327680), blk, 0, stream>>>(Ee, Ff, 327680);
  k_smul<<<nb(327680), blk, 0, stream>>>(Ff, sw1, sw2, sw3, sw4, Gg, 327680);
  k_inv_t<<<nb(655360), blk, 0, stream>>>(Gg, Cb, 655360);
  k_inv_x<<<nb(1310720), blk, 0, stream>>>(Cb, Bb, 1310720);
  k_inv_y<<<nb(5242880), blk, 0, stream>>>(Bb, A, 5242880);
  k_inv_z<<<nb(20971520), blk, 0, stream>>>(A, out, 20971520);

  // ---- pointwise path: += x2 ----
  k_x2<<<nb(1048576), blk, 0, stream>>>(x, w_pw, b_pw, out, 1048576);

  // ---- U-Net ----
  k_conv4d_pos<<<nb(65536), blk, 0, stream>>>(x, 20, nullptr, 0, c1_w, oc1,
                                              16, 32, 32, 16, 8, 16, 16, 8, 2, 65536);
  k_bn_stats<<<20, blk, 0, stream>>>(oc1, 16384, stats);
  k_bn_apply<<<nb(1310720), blk, 0, stream>>>(oc1, 16384, stats, bn1_g, bn1_b, 1310720);

  k_conv4d_elem<<<nb(81920), blk, 0, stream>>>(oc1, c2_w, oc2a, 20,
                                               8, 16, 16, 8, 4, 8, 8, 4, 2, 81920);
  k_bn_stats<<<20, blk, 0, stream>>>(oc2a, 1024, stats);
  k_bn_apply<<<nb(81920), blk, 0, stream>>>(oc2a, 1024, stats, bn2_g, bn2_b, 81920);

  k_conv4d_elem<<<nb(81920), blk, 0, stream>>>(oc2a, c21_w, oc2, 20,
                                               4, 8, 8, 4, 4, 8, 8, 4, 1, 81920);
  k_bn_stats<<<20, blk, 0, stream>>>(oc2, 1024, stats);
  k_bn_apply<<<nb(81920), blk, 0, stream>>>(oc2, 1024, stats, bn21_g, bn21_b, 81920);

  k_conv4d_elem<<<nb(5120), blk, 0, stream>>>(oc2, c3_w, oc3a, 20,
                                              4, 8, 8, 4, 2, 4, 4, 2, 2, 5120);
  k_bn_stats<<<20, blk, 0, stream>>>(oc3a, 64, stats);
  k_bn_apply<<<nb(5120), blk, 0, stream>>>(oc3a, 64, stats, bn3_g, bn3_b, 5120);

  k_conv4d_elem<<<nb(5120), blk, 0, stream>>>(oc3a, c31_w, oc3, 20,
                                              2, 4, 4, 2, 2, 4, 4, 2, 1, 5120);
  k_bn_stats<<<20, blk, 0, stream>>>(oc3, 64, stats);
  k_bn_apply<<<nb(5120), blk, 0, stream>>>(oc3, 64, stats, bn31_g, bn31_b, 5120);

  k_deconv4d<<<nb(4096), blk, 0, stream>>>(oc3, 20, nullptr, 0, d2_w, d2_b, od2,
                                           2, 4, 4, 2, 4096);
  k_deconv4d<<<nb(65536), blk, 0, stream>>>(oc2, 20, od2, 20, d1_w, d1_b, od1,
                                            4, 8, 8, 4, 65536);
  k_deconv4d<<<nb(1048576), blk, 0, stream>>>(oc1, 20, od1, 20, d0_w, d0_b, od0,
                                              8, 16, 16, 8, 1048576);

  k_conv4d_final<<<nb(1048576), blk, 0, stream>>>(x, od0, out_w, out_b, out, 1048576);
}

// Round 2
// 4597.083 us; speedup vs baseline: 2.0253x; 2.0253x over previous
//
#include <hip/hip_runtime.h>

#define PI2 6.28318530717958647692f

typedef __attribute__((ext_vector_type(8))) short bf16x8;
typedef __attribute__((ext_vector_type(4))) float f32x4;

__device__ __forceinline__ void cfma(float2& acc, float2 a, float2 b) {
  acc.x += a.x * b.x - a.y * b.y;
  acc.y += a.x * b.y + a.y * b.x;
}

__device__ __forceinline__ float2 twf(int m, float invN, float sign) {
  float a = sign * PI2 * (float)m * invN;
  float s, c;
  __sincosf(a, &s, &c);
  return make_float2(c, s);
}

__device__ __forceinline__ short f2bf(float f) {
  unsigned u = __float_as_uint(f);
  unsigned r = (u + 0x7fff + ((u >> 16) & 1)) >> 16;
  return (short)r;
}

// ---------------- spectral forward ----------------
__global__ void k_fwd_z(const float* __restrict__ x, float2* __restrict__ out, int nrows) {
  int r = blockIdx.x * 256 + threadIdx.x;
  if (r >= nrows) return;
  const float* p = x + (size_t)r * 16;
  float v[16];
#pragma unroll
  for (int z = 0; z < 16; z++) v[z] = p[z];
#pragma unroll
  for (int zk = 0; zk < 4; zk++) {
    float re = 0.f, im = 0.f;
#pragma unroll
    for (int z = 0; z < 16; z++) {
      float2 t = twf((z * zk) & 15, 1.f / 16.f, -1.f);
      re += v[z] * t.x;
      im += v[z] * t.y;
    }
    out[(size_t)r * 4 + zk] = make_float2(re, im);
  }
}

__global__ void k_fwd_y(const float2* __restrict__ in, float2* __restrict__ out, int n) {
  int i = blockIdx.x * 256 + threadIdx.x;
  if (i >= n) return;
  int zk = i & 3, yk = (i >> 2) & 7, slab = i >> 5;
  const float2* p = in + (size_t)slab * 128 + zk;
  float2 acc = make_float2(0.f, 0.f);
  for (int y = 0; y < 32; y++) cfma(acc, p[y * 4], twf((y * yk) & 31, 1.f / 32.f, -1.f));
  out[i] = acc;
}

__global__ void k_fwd_x(const float2* __restrict__ in, float2* __restrict__ out, int n) {
  int i = blockIdx.x * 256 + threadIdx.x;
  if (i >= n) return;
  int zk = i & 3, yk = (i >> 2) & 7, xi = (i >> 5) & 15, slab = i >> 9;
  int xk = (xi < 8) ? xi : xi + 16;
  const float2* p = in + (size_t)slab * 1024 + yk * 4 + zk;
  float2 acc = make_float2(0.f, 0.f);
  for (int xx = 0; xx < 32; xx++) cfma(acc, p[xx * 32], twf((xx * xk) & 31, 1.f / 32.f, -1.f));
  out[i] = acc;
}

__global__ void k_fwd_t(const float2* __restrict__ in, float2* __restrict__ out, int n) {
  int i = blockIdx.x * 256 + threadIdx.x;
  if (i >= n) return;
  int zk = i & 3, yk = (i >> 2) & 7, xi = (i >> 5) & 15, ti = (i >> 9) & 7, bc = i >> 12;
  int tk = (ti < 4) ? ti : ti + 8;
  const float2* p = in + (size_t)bc * 8192 + xi * 32 + yk * 4 + zk;
  float2 acc = make_float2(0.f, 0.f);
  for (int t = 0; t < 16; t++) cfma(acc, p[t * 512], twf((t * tk) & 15, 1.f / 16.f, -1.f));
  out[i] = acc;
}

__global__ void k_fwd_c(const float2* __restrict__ in, float2* __restrict__ out, int n) {
  int i = blockIdx.x * 256 + threadIdx.x;
  if (i >= n) return;
  int mode = i & 4095, r = i >> 12, ck = r % 20, b = r / 20;
  const float2* p = in + (size_t)b * 81920 + mode;
  float2 acc = make_float2(0.f, 0.f);
  for (int c = 0; c < 20; c++) cfma(acc, p[(size_t)c * 4096], twf((c * ck) % 20, 1.f / 20.f, -1.f));
  out[i] = acc;
}

__global__ void k_fwd_b(const float2* __restrict__ in, float2* __restrict__ out, int n) {
  int i = blockIdx.x * 256 + threadIdx.x;
  if (i >= n) return;
  int mode = i & 4095, r = i >> 12, ck = r % 20, bk = r / 20;
  const float2* p = in + (size_t)ck * 4096 + mode;
  float2 acc = make_float2(0.f, 0.f);
  for (int b = 0; b < 4; b++) cfma(acc, p[(size_t)b * 81920], twf((b * bk) & 3, 0.25f, -1.f));
  out[i] = acc;
}

__global__ void k_smul(const float2* __restrict__ in,
                       const float* __restrict__ sw1, const float* __restrict__ sw2,
                       const float* __restrict__ sw3, const float* __restrict__ sw4,
                       float2* __restrict__ out, int n) {
  int i = blockIdx.x * 256 + threadIdx.x;
  if (i >= n) return;
  int mode = i & 4095, r = i >> 12, o = r % 20, bk = r / 20;
  int ti = mode >> 9, xi = (mode >> 5) & 15, yk = (mode >> 2) & 7, zk = mode & 3;
  const float* w = (ti < 4) ? ((xi < 8) ? sw1 : sw3) : ((xi < 8) ? sw2 : sw4);
  int tl = ti & 3, xl = xi & 7;
  const float2* wp = (const float2*)w;
  const float2* ip = in + (size_t)bk * 81920 + mode;
  size_t wsub = (size_t)o * 1024 + (size_t)tl * 256 + (size_t)xl * 32 + yk * 4 + zk;
  float2 acc = make_float2(0.f, 0.f);
  for (int ci = 0; ci < 20; ci++) cfma(acc, ip[(size_t)ci * 4096], wp[(size_t)ci * 20480 + wsub]);
  out[i] = acc;
}

// ---------------- spectral inverse ----------------
__global__ void k_inv_t(const float2* __restrict__ in, float2* __restrict__ out, int n) {
  int i = blockIdx.x * 256 + threadIdx.x;
  if (i >= n) return;
  int zk = i & 3, yk = (i >> 2) & 7, xi = (i >> 5) & 15, tp = (i >> 9) & 15, bc = i >> 13;
  const float2* p = in + (size_t)bc * 4096 + xi * 32 + yk * 4 + zk;
  float2 acc = make_float2(0.f, 0.f);
  for (int ti = 0; ti < 8; ti++) {
    int tk = (ti < 4) ? ti : ti + 8;
    cfma(acc, p[ti * 512], twf((tk * tp) & 15, 1.f / 16.f, 1.f));
  }
  out[i] = acc;
}

__global__ void k_inv_x(const float2* __restrict__ in, float2* __restrict__ out, int n) {
  int i = blockIdx.x * 256 + threadIdx.x;
  if (i >= n) return;
  int zk = i & 3, yk = (i >> 2) & 7, xp = (i >> 5) & 31, tp = (i >> 10) & 15, bc = i >> 14;
  const float2* p = in + (size_t)bc * 8192 + tp * 512 + yk * 4 + zk;
  float2 acc = make_float2(0.f, 0.f);
  for (int xi = 0; xi < 16; xi++) {
    int xk = (xi < 8) ? xi : xi + 16;
    cfma(acc, p[xi * 32], twf((xk * xp) & 31, 1.f / 32.f, 1.f));
  }
  out[i] = acc;
}

__global__ void k_inv_y(const float2* __restrict__ in, float2* __restrict__ out, int n) {
  int i = blockIdx.x * 256 + threadIdx.x;
  if (i >= n) return;
  int zk = i & 3, yp = (i >> 2) & 31, xp = (i >> 7) & 31, tp = (i >> 12) & 15, bc = i >> 16;
  const float2* p = in + (size_t)bc * 16384 + tp * 1024 + xp * 32 + zk;
  float2 acc = make_float2(0.f, 0.f);
  for (int yk = 0; yk < 8; yk++) cfma(acc, p[yk * 4], twf((yk * yp) & 31, 1.f / 32.f, 1.f));
  out[i] = acc;
}

__global__ void k_inv_z(const float2* __restrict__ in, float* __restrict__ out, int n) {
  int i = blockIdx.x * 256 + threadIdx.x;
  if (i >= n) return;
  int zp = i & 15, row = i >> 4;
  const float2* p = in + (size_t)row * 4;
  float val = p[0].x;
#pragma unroll
  for (int zk = 1; zk < 4; zk++) {
    float2 t = twf((zk * zp) & 15, 1.f / 16.f, 1.f);
    val += 2.f * (p[zk].x * t.x - p[zk].y * t.y);
  }
  out[i] = val * (1.f / 262144.f);
}

// ---------------- pointwise path (adds into d_out) ----------------
__global__ void k_x2(const float* __restrict__ x, const float* __restrict__ w,
                     const float* __restrict__ bias, float* __restrict__ out, int n) {
  int i = blockIdx.x * 256 + threadIdx.x;
  if (i >= n) return;
  int s = i & 262143, b = i >> 18;
  float xv[20];
#pragma unroll
  for (int c = 0; c < 20; c++) xv[c] = x[((size_t)b * 20 + c) * 262144 + s];
#pragma unroll
  for (int o = 0; o < 20; o++) {
    float a = bias[o];
#pragma unroll
    for (int c = 0; c < 20; c++) a += w[o * 20 + c] * xv[c];
    out[((size_t)b * 20 + o) * 262144 + s] += a;
  }
}

// ---------------- U-Net: convs ----------------
__global__ void k_conv4d_pos(const float* __restrict__ in1, int Ci1,
                             const float* __restrict__ in2, int Ci2,
                             const float* __restrict__ W, float* __restrict__ out,
                             int Ti, int Xi, int Yi, int Zi,
                             int To, int Xo, int Yo, int Zo, int stride, int n) {
  int idx = blockIdx.x * 256 + threadIdx.x;
  if (idx >= n) return;
  int zo = idx % Zo; int r = idx / Zo;
  int yo = r % Yo; r /= Yo;
  int xo = r % Xo; r /= Xo;
  int to = r % To; int b = r / To;
  float acc[20];
#pragma unroll
  for (int o = 0; o < 20; o++) acc[o] = 0.f;
  int Ci = Ci1 + Ci2;
  size_t in_sp = (size_t)Ti * Xi * Yi * Zi;
  for (int ci = 0; ci < Ci; ci++) {
    const float* base = (ci < Ci1) ? in1 + ((size_t)b * Ci1 + ci) * in_sp
                                   : in2 + ((size_t)b * Ci2 + (ci - Ci1)) * in_sp;
    const float* wc = W + (size_t)ci * 81;
    for (int kt = 0; kt < 3; kt++) {
      int t = to * stride + kt - 1; if (t < 0 || t >= Ti) continue;
      for (int kx = 0; kx < 3; kx++) {
        int xx = xo * stride + kx - 1; if (xx < 0 || xx >= Xi) continue;
        for (int ky = 0; ky < 3; ky++) {
          int y = yo * stride + ky - 1; if (y < 0 || y >= Yi) continue;
          for (int kz = 0; kz < 3; kz++) {
            int z = zo * stride + kz - 1; if (z < 0 || z >= Zi) continue;
            float v = base[(((size_t)t * Xi + xx) * Yi + y) * Zi + z];
            int tap = ((kt * 3 + kx) * 3 + ky) * 3 + kz;
#pragma unroll
            for (int o = 0; o < 20; o++) acc[o] += v * wc[(size_t)o * Ci * 81 + tap];
          }
        }
      }
    }
  }
  size_t osp = (size_t)To * Xo * Yo * Zo;
  size_t obase = (size_t)b * 20 * osp + (((size_t)to * Xo + xo) * Yo + yo) * Zo + zo;
#pragma unroll
  for (int o = 0; o < 20; o++) out[obase + (size_t)o * osp] = acc[o];
}

__global__ void k_conv4d_elem(const float* __restrict__ in, const float* __restrict__ W,
                              float* __restrict__ out, int Ci,
                              int Ti, int Xi, int Yi, int Zi,
                              int To, int Xo, int Yo, int Zo, int stride, int n) {
  int idx = blockIdx.x * 256 + threadIdx.x;
  if (idx >= n) return;
  int zo = idx % Zo; int r = idx / Zo;
  int yo = r % Yo; r /= Yo;
  int xo = r % Xo; r /= Xo;
  int to = r % To; r /= To;
  int o = r % 20; int b = r / 20;
  float acc = 0.f;
  size_t in_sp = (size_t)Ti * Xi * Yi * Zi;
  for (int ci = 0; ci < Ci; ci++) {
    const float* base = in + ((size_t)b * Ci + ci) * in_sp;
    const float* wc = W + ((size_t)o * Ci + ci) * 81;
    for (int kt = 0; kt < 3; kt++) {
      int t = to * stride + kt - 1; if (t < 0 || t >= Ti) continue;
      for (int kx = 0; kx < 3; kx++) {
        int xx = xo * stride + kx - 1; if (xx < 0 || xx >= Xi) continue;
        for (int ky = 0; ky < 3; ky++) {
          int y = yo * stride + ky - 1; if (y < 0 || y >= Yi) continue;
          for (int kz = 0; kz < 3; kz++) {
            int z = zo * stride + kz - 1; if (z < 0 || z >= Zi) continue;
            acc += base[(((size_t)t * Xi + xx) * Yi + y) * Zi + z] * wc[((kt * 3 + kx) * 3 + ky) * 3 + kz];
          }
        }
      }
    }
  }
  out[idx] = acc;
}

// ---------------- BN ----------------
__global__ void k_bn_stats(const float* __restrict__ d, int S, float* __restrict__ stats) {
  int c = blockIdx.x;
  int tid = threadIdx.x;
  float s = 0.f, s2 = 0.f;
  for (int b = 0; b < 4; b++) {
    const float* p = d + ((size_t)b * 20 + c) * S;
    for (int i = tid; i < S; i += 256) { float v = p[i]; s += v; s2 += v * v; }
  }
  __shared__ float ls[256], lq[256];
  ls[tid] = s; lq[tid] = s2;
  __syncthreads();
  for (int off = 128; off > 0; off >>= 1) {
    if (tid < off) { ls[tid] += ls[tid + off]; lq[tid] += lq[tid + off]; }
    __syncthreads();
  }
  if (tid == 0) {
    float cnt = 4.f * (float)S;
    float mean = ls[0] / cnt;
    float var = lq[0] / cnt - mean * mean;
    stats[2 * c] = mean;
    stats[2 * c + 1] = rsqrtf(var + 1e-5f);
  }
}

__global__ void k_bn_apply(float* __restrict__ d, int S, const float* __restrict__ stats,
                           const float* __restrict__ g, const float* __restrict__ bb, int n) {
  int idx = blockIdx.x * 256 + threadIdx.x;
  if (idx >= n) return;
  int c = (idx / S) % 20;
  float v = d[idx];
  v = (v - stats[2 * c]) * stats[2 * c + 1] * g[c] + bb[c];
  d[idx] = (v >= 0.f) ? v : 0.1f * v;
}

// ---------------- deconv (ConvTranspose4d k=4 s=2 p=1), bias+lrelu fused ----------------
__device__ __forceinline__ int dcands(int p, int n_in, int* q, int* k) {
  int cnt = 0;
  int q0 = (p + 1) >> 1, k0 = p + 1 - 2 * q0;
  if (q0 >= 0 && q0 < n_in) { q[cnt] = q0; k[cnt] = k0; cnt++; }
  int q1 = q0 - 1, k1 = k0 + 2;
  if (q1 >= 0 && q1 < n_in) { q[cnt] = q1; k[cnt] = k1; cnt++; }
  return cnt;
}

__global__ void k_deconv4d(const float* __restrict__ in1, int Ci1,
                           const float* __restrict__ in2, int Ci2,
                           const float* __restrict__ W, const float* __restrict__ bias,
                           float* __restrict__ out,
                           int Ti, int Xi, int Yi, int Zi, int n) {
  int idx = blockIdx.x * 256 + threadIdx.x;
  if (idx >= n) return;
  int To = 2 * Ti, Xo = 2 * Xi, Yo = 2 * Yi, Zo = 2 * Zi;
  int zo = idx % Zo; int r = idx / Zo;
  int yo = r % Yo; r /= Yo;
  int xo = r % Xo; r /= Xo;
  int to = r % To; int b = r / To;
  int qt[2], kt[2], qx[2], kx[2], qy[2], ky[2], qz[2], kz[2];
  int nt = dcands(to, Ti, qt, kt), nx = dcands(xo, Xi, qx, kx);
  int ny = dcands(yo, Yi, qy, ky), nz = dcands(zo, Zi, qz, kz);
  float acc[20];
#pragma unroll
  for (int o = 0; o < 20; o++) acc[o] = 0.f;
  int Ci = Ci1 + Ci2;
  size_t in_sp = (size_t)Ti * Xi * Yi * Zi;
  for (int ci = 0; ci < Ci; ci++) {
    const float* base = (ci < Ci1) ? in1 + ((size_t)b * Ci1 + ci) * in_sp
                                   : in2 + ((size_t)b * Ci2 + (ci - Ci1)) * in_sp;
    const float* wc = W + (size_t)ci * 5120;  // [ci][o(20)][256]
    for (int it = 0; it < nt; it++)
      for (int ix = 0; ix < nx; ix++)
        for (int iy = 0; iy < ny; iy++)
          for (int iz = 0; iz < nz; iz++) {
            float v = base[(((size_t)qt[it] * Xi + qx[ix]) * Yi + qy[iy]) * Zi + qz[iz]];
            int tap = ((kt[it] * 4 + kx[ix]) * 4 + ky[iy]) * 4 + kz[iz];
#pragma unroll
            for (int o = 0; o < 20; o++) acc[o] += v * wc[o * 256 + tap];
          }
  }
  size_t osp = (size_t)To * Xo * Yo * Zo;
  size_t obase = (size_t)b * 20 * osp + (((size_t)to * Xo + xo) * Yo + yo) * Zo + zo;
#pragma unroll
  for (int o = 0; o < 20; o++) {
    float v2 = acc[o] + bias[o];
    out[obase + (size_t)o * osp] = (v2 >= 0.f) ? v2 : 0.1f * v2;
  }
}

// d0 deconv: writes bf16 channels-last into Xcl at ci 20..39 (fused lrelu+cvt).
// dims fixed: in 8x16x16x8, out 16x32x32x16, Ci=40 (oc1 | od1)
__global__ void k_deconv4d_cl(const float* __restrict__ in1, const float* __restrict__ in2,
                              const float* __restrict__ W, const float* __restrict__ bias,
                              short* __restrict__ Xcl, int n) {
  int idx = blockIdx.x * 256 + threadIdx.x;
  if (idx >= n) return;
  int zo = idx & 15; int r = idx >> 4;
  int yo = r & 31; r >>= 5;
  int xo = r & 31; r >>= 5;
  int to = r & 15; int b = r >> 4;
  int qt[2], kt[2], qx[2], kx[2], qy[2], ky[2], qz[2], kz[2];
  int nt = dcands(to, 8, qt, kt), nx = dcands(xo, 16, qx, kx);
  int ny = dcands(yo, 16, qy, ky), nz = dcands(zo, 8, qz, kz);
  float acc[20];
#pragma unroll
  for (int o = 0; o < 20; o++) acc[o] = 0.f;
  const size_t in_sp = 8 * 16 * 16 * 8;
  for (int ci = 0; ci < 40; ci++) {
    const float* base = (ci < 20) ? in1 + ((size_t)b * 20 + ci) * in_sp
                                  : in2 + ((size_t)b * 20 + (ci - 20)) * in_sp;
    const float* wc = W + (size_t)ci * 5120;
    for (int it = 0; it < nt; it++)
      for (int ix = 0; ix < nx; ix++)
        for (int iy = 0; iy < ny; iy++)
          for (int iz = 0; iz < nz; iz++) {
            float v = base[(((size_t)qt[it] * 16 + qx[ix]) * 16 + qy[iy]) * 8 + qz[iz]];
            int tap = ((kt[it] * 4 + kx[ix]) * 4 + ky[iy]) * 4 + kz[iz];
#pragma unroll
            for (int o = 0; o < 20; o++) acc[o] += v * wc[o * 256 + tap];
          }
  }
  size_t pos = ((((size_t)b * 16 + to) * 32 + xo) * 32 + yo) * 16 + zo;
  short* dst = Xcl + pos * 40 + 20;
#pragma unroll
  for (int o = 0; o < 20; o++) {
    float v2 = acc[o] + bias[o];
    v2 = (v2 >= 0.f) ? v2 : 0.1f * v2;
    dst[o] = f2bf(v2);
  }
}

// fill Xcl ci 0..19 from x (fp32 [c][spatial] -> bf16 channels-last)
__global__ void k_xcl_x(const float* __restrict__ x, short* __restrict__ Xcl, int n) {
  int i = blockIdx.x * 256 + threadIdx.x;
  if (i >= n) return;
  int s = i & 262143, b = i >> 18;
  short* dst = Xcl + (size_t)i * 40;
  const float* src = x + (size_t)b * 20 * 262144 + s;
#pragma unroll
  for (int c = 0; c < 20; c++) dst[c] = f2bf(src[(size_t)c * 262144]);
}

// pack out_w [20][40][81] -> Wp[tap(81)][mtile(2)][m(16)][k(64)] bf16, zero-padded.
// also zero the 128B zero-page.
__global__ void k_pack_w(const float* __restrict__ out_w, short* __restrict__ Wp,
                         short* __restrict__ zp, int n) {
  int i = blockIdx.x * 256 + threadIdx.x;
  if (i >= n) return;
  int k = i & 63, m = (i >> 6) & 15, mt = (i >> 10) & 1, tap = i >> 11;
  int o = mt * 16 + m;
  float v = (o < 20 && k < 40) ? out_w[((size_t)o * 40 + k) * 81 + tap] : 0.f;
  Wp[i] = f2bf(v);
  if (i < 64) zp[i] = 0;
}

// ---------------- final conv: bf16 MFMA implicit GEMM ----------------
// D[o][z] per tile: A = Wp (M=o16, K=ci), B = Xcl (K=ci, N=z16), 81 taps, K pad 40->64.
// grid: (b, t0, x0, yb) = 4*16*32*2 = 4096 WGs; wave w covers y = yb*16 + w*4 + nt.
__global__ __launch_bounds__(256) void k_fconv_mfma(
    const short* __restrict__ Xcl, const short* __restrict__ Wp,
    const short* __restrict__ zp, const float* __restrict__ bias,
    float* __restrict__ io) {
  int bid = blockIdx.x;
  int yb = bid & 1, x0 = (bid >> 1) & 31, t0 = (bid >> 6) & 15, b = bid >> 10;
  int lane = threadIdx.x & 63, wave = threadIdx.x >> 6;
  int ln15 = lane & 15, kg = lane >> 4;
  int ybase = yb * 16 + wave * 4;

  f32x4 acc[2][4];
#pragma unroll
  for (int mt = 0; mt < 2; mt++)
#pragma unroll
    for (int nt = 0; nt < 4; nt++)
#pragma unroll
      for (int j = 0; j < 4; j++) acc[mt][nt][j] = 0.f;

  const char* xb = (const char*)Xcl;
  const char* wb = (const char*)Wp;
  const char* zb = (const char*)zp;

  for (int kt = 0; kt < 3; kt++) {
    int ti = t0 + kt - 1;
    if (ti < 0 || ti > 15) continue;
    for (int kx = 0; kx < 3; kx++) {
      int xi = x0 + kx - 1;
      if (xi < 0 || xi > 31) continue;
      long rowbase = ((long)((b * 16 + ti) * 32 + xi)) * 32;
      for (int ky = 0; ky < 3; ky++) {
#pragma unroll
        for (int kz = 0; kz < 3; kz++) {
          int tap = ((kt * 3 + kx) * 3 + ky) * 3 + kz;
          int zi = ln15 + kz - 1;
          bool zok = (zi >= 0) && (zi < 16);
          const char* wt = wb + (size_t)tap * 4096;
#pragma unroll
          for (int ch = 0; ch < 2; ch++) {
            bf16x8 a0 = *(const bf16x8*)(wt + ln15 * 128 + ch * 64 + kg * 16);
            bf16x8 a1 = *(const bf16x8*)(wt + 2048 + ln15 * 128 + ch * 64 + kg * 16);
#pragma unroll
            for (int nt = 0; nt < 4; nt++) {
              int yi = ybase + nt + ky - 1;
              if (yi < 0 || yi > 31) continue;
              long pos = (rowbase + yi) * 16 + (long)zi;
              const char* src = zok ? (xb + pos * 80 + ch * 64 + kg * 16)
                                    : (zb + ch * 64 + kg * 16);
              bf16x8 bv = *(const bf16x8*)src;
              acc[0][nt] = __builtin_amdgcn_mfma_f32_16x16x32_bf16(a0, bv, acc[0][nt], 0, 0, 0);
              acc[1][nt] = __builtin_amdgcn_mfma_f32_16x16x32_bf16(a1, bv, acc[1][nt], 0, 0, 0);
            }
          }
        }
      }
    }
  }

  // epilogue: D col = lane&15 = z, row = kg*4 + reg = o (within mtile)
#pragma unroll
  for (int mt = 0; mt < 2; mt++)
#pragma unroll
    for (int r = 0; r < 4; r++) {
      int o = mt * 16 + kg * 4 + r;
      if (o >= 20) continue;
      float bo = bias[o];
#pragma unroll
      for (int nt = 0; nt < 4; nt++) {
        int y = ybase + nt;
        size_t oidx = ((size_t)(b * 20 + o)) * 262144 +
                      ((((size_t)t0 * 32 + x0) * 32 + y) * 16 + ln15);
        float v = acc[mt][nt][r] + bo + io[oidx];
        io[oidx] = fmaxf(v, 0.f);
      }
    }
}

extern "C" void kernel_launch(void* const* d_in, const int* in_sizes, int n_in,
                              void* d_out, int out_size, void* d_ws, size_t ws_size,
                              hipStream_t stream) {
  const float* x     = (const float*)d_in[0];
  const float* sw1   = (const float*)d_in[1];
  const float* sw2   = (const float*)d_in[2];
  const float* sw3   = (const float*)d_in[3];
  const float* sw4   = (const float*)d_in[4];
  const float* w_pw  = (const float*)d_in[5];
  const float* b_pw  = (const float*)d_in[6];
  const float* c1_w  = (const float*)d_in[7];
  const float* c2_w  = (const float*)d_in[8];
  const float* c21_w = (const float*)d_in[9];
  const float* c3_w  = (const float*)d_in[10];
  const float* c31_w = (const float*)d_in[11];
  const float* bn1_g = (const float*)d_in[12];
  const float* bn1_b = (const float*)d_in[13];
  const float* bn2_g = (const float*)d_in[14];
  const float* bn2_b = (const float*)d_in[15];
  const float* bn21_g = (const float*)d_in[16];
  const float* bn21_b = (const float*)d_in[17];
  const float* bn3_g = (const float*)d_in[18];
  const float* bn3_b = (const float*)d_in[19];
  const float* bn31_g = (const float*)d_in[20];
  const float* bn31_b = (const float*)d_in[21];
  const float* d2_w  = (const float*)d_in[22];
  const float* d2_b  = (const float*)d_in[23];
  const float* d1_w  = (const float*)d_in[24];
  const float* d1_b  = (const float*)d_in[25];
  const float* d0_w  = (const float*)d_in[26];
  const float* d0_b  = (const float*)d_in[27];
  const float* out_w = (const float*)d_in[28];
  const float* out_b = (const float*)d_in[29];
  float* out = (float*)d_out;
  float* ws = (float*)d_ws;

  // spectral arena (phase 1, overlaid later)
  float2* A  = (float2*)(ws);
  float2* Bb = (float2*)(ws + 10485760);
  float2* Cb = (float2*)(ws + 13107200);
  float2* Dd = (float2*)(ws + 14417920);
  float2* Ee = (float2*)(ws + 15073280);
  float2* Ff = (float2*)(ws + 15728640);
  float2* Gg = (float2*)(ws + 16384000);

  // U-Net arena
  float* oc1   = ws;             // 1,310,720 floats
  float* oc2a  = ws + 1310720;   //    81,920
  float* oc2   = ws + 1392640;   //    81,920
  float* oc3a  = ws + 1474560;   //     5,120
  float* oc3   = ws + 1479680;   //     5,120
  float* od2   = ws + 1484800;   //    81,920
  float* od1   = ws + 1566720;   // 1,310,720
  short* Xcl   = (short*)(ws + 2877440);  // 41,943,040 bf16 = 83.9 MB (old od0 slot)
  float* stats = ws + 23848960;  // 40
  // Wp + zeropage overlay the dead oc2a/oc2 region (only used after d1 deconv)
  short* Wp = (short*)(ws + 1310720);     // 165,888 bf16
  short* zp = (short*)(ws + 1393664);     // 64 bf16 (128 B)

  auto nb = [](int n) { return (n + 255) / 256; };
  dim3 blk(256);

  // ---- spectral path: x1 -> d_out ----
  k_fwd_z<<<nb(1310720), blk, 0, stream>>>(x, A, 1310720);
  k_fwd_y<<<nb(1310720), blk, 0, stream>>>(A, Bb, 1310720);
  k_fwd_x<<<nb(655360), blk, 0, stream>>>(Bb, Cb, 655360);
  k_fwd_t<<<nb(327680), blk, 0, stream>>>(Cb, Dd, 327680);
  k_fwd_c<<<nb(327680), blk, 0, stream>>>(Dd, Ee, 327680);
  k_fwd_b<<<nb(327680), blk, 0, stream>>>(Ee, Ff, 327680);
  k_smul<<<nb(327680), blk, 0, stream>>>(Ff, sw1, sw2, sw3, sw4, Gg, 327680);
  k_inv_t<<<nb(655360), blk, 0, stream>>>(Gg, Cb, 655360);
  k_inv_x<<<nb(1310720), blk, 0, stream>>>(Cb, Bb, 1310720);
  k_inv_y<<<nb(5242880), blk, 0, stream>>>(Bb, A, 5242880);
  k_inv_z<<<nb(20971520), blk, 0, stream>>>(A, out, 20971520);

  // ---- pointwise path: += x2 ----
  k_x2<<<nb(1048576), blk, 0, stream>>>(x, w_pw, b_pw, out, 1048576);

  // ---- Xcl ci 0..19 from x (spectral arena is dead now) ----
  k_xcl_x<<<nb(1048576), blk, 0, stream>>>(x, Xcl, 1048576);

  // ---- U-Net ----
  k_conv4d_pos<<<nb(65536), blk, 0, stream>>>(x, 20, nullptr, 0, c1_w, oc1,
                                              16, 32, 32, 16, 8, 16, 16, 8, 2, 65536);
  k_bn_stats<<<20, blk, 0, stream>>>(oc1, 16384, stats);
  k_bn_apply<<<nb(1310720), blk, 0, stream>>>(oc1, 16384, stats, bn1_g, bn1_b, 1310720);

  k_conv4d_elem<<<nb(81920), blk, 0, stream>>>(oc1, c2_w, oc2a, 20,
                                               8, 16, 16, 8, 4, 8, 8, 4, 2, 81920);
  k_bn_stats<<<20, blk, 0, stream>>>(oc2a, 1024, stats);
  k_bn_apply<<<nb(81920), blk, 0, stream>>>(oc2a, 1024, stats, bn2_g, bn2_b, 81920);

  k_conv4d_elem<<<nb(81920), blk, 0, stream>>>(oc2a, c21_w, oc2, 20,
                                               4, 8, 8, 4, 4, 8, 8, 4, 1, 81920);
  k_bn_stats<<<20, blk, 0, stream>>>(oc2, 1024, stats);
  k_bn_apply<<<nb(81920), blk, 0, stream>>>(oc2, 1024, stats, bn21_g, bn21_b, 81920);

  k_conv4d_elem<<<nb(5120), blk, 0, stream>>>(oc2, c3_w, oc3a, 20,
                                              4, 8, 8, 4, 2, 4, 4, 2, 2, 5120);
  k_bn_stats<<<20, blk, 0, stream>>>(oc3a, 64, stats);
  k_bn_apply<<<nb(5120), blk, 0, stream>>>(oc3a, 64, stats, bn3_g, bn3_b, 5120);

  k_conv4d_elem<<<nb(5120), blk, 0, stream>>>(oc3a, c31_w, oc3, 20,
                                              2, 4, 4, 2, 2, 4, 4, 2, 1, 5120);
  k_bn_stats<<<20, blk, 0, stream>>>(oc3, 64, stats);
  k_bn_apply<<<nb(5120), blk, 0, stream>>>(oc3, 64, stats, bn31_g, bn31_b, 5120);

  k_deconv4d<<<nb(4096), blk, 0, stream>>>(oc3, 20, nullptr, 0, d2_w, d2_b, od2,
                                           2, 4, 4, 2, 4096);
  k_deconv4d<<<nb(65536), blk, 0, stream>>>(oc2, 20, od2, 20, d1_w, d1_b, od1,
                                            4, 8, 8, 4, 65536);

  // pack weights (overlays dead oc2a/oc2 region) + zero-page
  k_pack_w<<<nb(165888), blk, 0, stream>>>(out_w, Wp, zp, 165888);

  // d0 deconv -> Xcl ci 20..39 (bf16 channels-last, lrelu fused)
  k_deconv4d_cl<<<nb(1048576), blk, 0, stream>>>(oc1, od1, d0_w, d0_b, Xcl, 1048576);

  // final conv via MFMA, fused +bias +x1+x2 +relu into d_out
  k_fconv_mfma<<<4096, blk, 0, stream>>>(Xcl, Wp, zp, out_b, out);
}

// Round 3
// 3704.748 us; speedup vs baseline: 2.5132x; 1.2409x over previous
//
#include <hip/hip_runtime.h>

#define PI2 6.28318530717958647692f

typedef __attribute__((ext_vector_type(8))) short bf16x8;
typedef __attribute__((ext_vector_type(4))) float f32x4;

__device__ __forceinline__ void cfma(float2& acc, float2 a, float2 b) {
  acc.x += a.x * b.x - a.y * b.y;
  acc.y += a.x * b.y + a.y * b.x;
}

__device__ __forceinline__ float2 twf(int m, float invN, float sign) {
  float a = sign * PI2 * (float)m * invN;
  float s, c;
  __sincosf(a, &s, &c);
  return make_float2(c, s);
}

__device__ __forceinline__ short f2bf(float f) {
  unsigned u = __float_as_uint(f);
  unsigned r = (u + 0x7fff + ((u >> 16) & 1)) >> 16;
  return (short)r;
}

// ---------------- spectral forward ----------------
__global__ void k_fwd_z(const float* __restrict__ x, float2* __restrict__ out, int nrows) {
  int r = blockIdx.x * 256 + threadIdx.x;
  if (r >= nrows) return;
  const float* p = x + (size_t)r * 16;
  float v[16];
#pragma unroll
  for (int z = 0; z < 16; z++) v[z] = p[z];
#pragma unroll
  for (int zk = 0; zk < 4; zk++) {
    float re = 0.f, im = 0.f;
#pragma unroll
    for (int z = 0; z < 16; z++) {
      float2 t = twf((z * zk) & 15, 1.f / 16.f, -1.f);
      re += v[z] * t.x;
      im += v[z] * t.y;
    }
    out[(size_t)r * 4 + zk] = make_float2(re, im);
  }
}

__global__ void k_fwd_y(const float2* __restrict__ in, float2* __restrict__ out, int n) {
  int i = blockIdx.x * 256 + threadIdx.x;
  if (i >= n) return;
  int zk = i & 3, yk = (i >> 2) & 7, slab = i >> 5;
  const float2* p = in + (size_t)slab * 128 + zk;
  float2 acc = make_float2(0.f, 0.f);
  for (int y = 0; y < 32; y++) cfma(acc, p[y * 4], twf((y * yk) & 31, 1.f / 32.f, -1.f));
  out[i] = acc;
}

__global__ void k_fwd_x(const float2* __restrict__ in, float2* __restrict__ out, int n) {
  int i = blockIdx.x * 256 + threadIdx.x;
  if (i >= n) return;
  int zk = i & 3, yk = (i >> 2) & 7, xi = (i >> 5) & 15, slab = i >> 9;
  int xk = (xi < 8) ? xi : xi + 16;
  const float2* p = in + (size_t)slab * 1024 + yk * 4 + zk;
  float2 acc = make_float2(0.f, 0.f);
  for (int xx = 0; xx < 32; xx++) cfma(acc, p[xx * 32], twf((xx * xk) & 31, 1.f / 32.f, -1.f));
  out[i] = acc;
}

__global__ void k_fwd_t(const float2* __restrict__ in, float2* __restrict__ out, int n) {
  int i = blockIdx.x * 256 + threadIdx.x;
  if (i >= n) return;
  int zk = i & 3, yk = (i >> 2) & 7, xi = (i >> 5) & 15, ti = (i >> 9) & 7, bc = i >> 12;
  int tk = (ti < 4) ? ti : ti + 8;
  const float2* p = in + (size_t)bc * 8192 + xi * 32 + yk * 4 + zk;
  float2 acc = make_float2(0.f, 0.f);
  for (int t = 0; t < 16; t++) cfma(acc, p[t * 512], twf((t * tk) & 15, 1.f / 16.f, -1.f));
  out[i] = acc;
}

__global__ void k_fwd_c(const float2* __restrict__ in, float2* __restrict__ out, int n) {
  int i = blockIdx.x * 256 + threadIdx.x;
  if (i >= n) return;
  int mode = i & 4095, r = i >> 12, ck = r % 20, b = r / 20;
  const float2* p = in + (size_t)b * 81920 + mode;
  float2 acc = make_float2(0.f, 0.f);
  for (int c = 0; c < 20; c++) cfma(acc, p[(size_t)c * 4096], twf((c * ck) % 20, 1.f / 20.f, -1.f));
  out[i] = acc;
}

__global__ void k_fwd_b(const float2* __restrict__ in, float2* __restrict__ out, int n) {
  int i = blockIdx.x * 256 + threadIdx.x;
  if (i >= n) return;
  int mode = i & 4095, r = i >> 12, ck = r % 20, bk = r / 20;
  const float2* p = in + (size_t)ck * 4096 + mode;
  float2 acc = make_float2(0.f, 0.f);
  for (int b = 0; b < 4; b++) cfma(acc, p[(size_t)b * 81920], twf((b * bk) & 3, 0.25f, -1.f));
  out[i] = acc;
}

__global__ void k_smul(const float2* __restrict__ in,
                       const float* __restrict__ sw1, const float* __restrict__ sw2,
                       const float* __restrict__ sw3, const float* __restrict__ sw4,
                       float2* __restrict__ out, int n) {
  int i = blockIdx.x * 256 + threadIdx.x;
  if (i >= n) return;
  int mode = i & 4095, r = i >> 12, o = r % 20, bk = r / 20;
  int ti = mode >> 9, xi = (mode >> 5) & 15, yk = (mode >> 2) & 7, zk = mode & 3;
  const float* w = (ti < 4) ? ((xi < 8) ? sw1 : sw3) : ((xi < 8) ? sw2 : sw4);
  int tl = ti & 3, xl = xi & 7;
  const float2* wp = (const float2*)w;
  const float2* ip = in + (size_t)bk * 81920 + mode;
  size_t wsub = (size_t)o * 1024 + (size_t)tl * 256 + (size_t)xl * 32 + yk * 4 + zk;
  float2 acc = make_float2(0.f, 0.f);
  for (int ci = 0; ci < 20; ci++) cfma(acc, ip[(size_t)ci * 4096], wp[(size_t)ci * 20480 + wsub]);
  out[i] = acc;
}

// ---------------- spectral inverse ----------------
__global__ void k_inv_t(const float2* __restrict__ in, float2* __restrict__ out, int n) {
  int i = blockIdx.x * 256 + threadIdx.x;
  if (i >= n) return;
  int zk = i & 3, yk = (i >> 2) & 7, xi = (i >> 5) & 15, tp = (i >> 9) & 15, bc = i >> 13;
  const float2* p = in + (size_t)bc * 4096 + xi * 32 + yk * 4 + zk;
  float2 acc = make_float2(0.f, 0.f);
  for (int ti = 0; ti < 8; ti++) {
    int tk = (ti < 4) ? ti : ti + 8;
    cfma(acc, p[ti * 512], twf((tk * tp) & 15, 1.f / 16.f, 1.f));
  }
  out[i] = acc;
}

__global__ void k_inv_x(const float2* __restrict__ in, float2* __restrict__ out, int n) {
  int i = blockIdx.x * 256 + threadIdx.x;
  if (i >= n) return;
  int zk = i & 3, yk = (i >> 2) & 7, xp = (i >> 5) & 31, tp = (i >> 10) & 15, bc = i >> 14;
  const float2* p = in + (size_t)bc * 8192 + tp * 512 + yk * 4 + zk;
  float2 acc = make_float2(0.f, 0.f);
  for (int xi = 0; xi < 16; xi++) {
    int xk = (xi < 8) ? xi : xi + 16;
    cfma(acc, p[xi * 32], twf((xk * xp) & 31, 1.f / 32.f, 1.f));
  }
  out[i] = acc;
}

__global__ void k_inv_y(const float2* __restrict__ in, float2* __restrict__ out, int n) {
  int i = blockIdx.x * 256 + threadIdx.x;
  if (i >= n) return;
  int zk = i & 3, yp = (i >> 2) & 31, xp = (i >> 7) & 31, tp = (i >> 12) & 15, bc = i >> 16;
  const float2* p = in + (size_t)bc * 16384 + tp * 1024 + xp * 32 + zk;
  float2 acc = make_float2(0.f, 0.f);
  for (int yk = 0; yk < 8; yk++) cfma(acc, p[yk * 4], twf((yk * yp) & 31, 1.f / 32.f, 1.f));
  out[i] = acc;
}

__global__ void k_inv_z(const float2* __restrict__ in, float* __restrict__ out, int n) {
  int i = blockIdx.x * 256 + threadIdx.x;
  if (i >= n) return;
  int zp = i & 15, row = i >> 4;
  const float2* p = in + (size_t)row * 4;
  float val = p[0].x;
#pragma unroll
  for (int zk = 1; zk < 4; zk++) {
    float2 t = twf((zk * zp) & 15, 1.f / 16.f, 1.f);
    val += 2.f * (p[zk].x * t.x - p[zk].y * t.y);
  }
  out[i] = val * (1.f / 262144.f);
}

// ---------------- pointwise path (adds into d_out) ----------------
__global__ void k_x2(const float* __restrict__ x, const float* __restrict__ w,
                     const float* __restrict__ bias, float* __restrict__ out, int n) {
  int i = blockIdx.x * 256 + threadIdx.x;
  if (i >= n) return;
  int s = i & 262143, b = i >> 18;
  float xv[20];
#pragma unroll
  for (int c = 0; c < 20; c++) xv[c] = x[((size_t)b * 20 + c) * 262144 + s];
#pragma unroll
  for (int o = 0; o < 20; o++) {
    float a = bias[o];
#pragma unroll
    for (int c = 0; c < 20; c++) a += w[o * 20 + c] * xv[c];
    out[((size_t)b * 20 + o) * 262144 + s] += a;
  }
}

// ---------------- U-Net: convs ----------------
__global__ void k_conv4d_pos(const float* __restrict__ in1, int Ci1,
                             const float* __restrict__ in2, int Ci2,
                             const float* __restrict__ W, float* __restrict__ out,
                             int Ti, int Xi, int Yi, int Zi,
                             int To, int Xo, int Yo, int Zo, int stride, int n) {
  int idx = blockIdx.x * 256 + threadIdx.x;
  if (idx >= n) return;
  int zo = idx % Zo; int r = idx / Zo;
  int yo = r % Yo; r /= Yo;
  int xo = r % Xo; r /= Xo;
  int to = r % To; int b = r / To;
  float acc[20];
#pragma unroll
  for (int o = 0; o < 20; o++) acc[o] = 0.f;
  int Ci = Ci1 + Ci2;
  size_t in_sp = (size_t)Ti * Xi * Yi * Zi;
  for (int ci = 0; ci < Ci; ci++) {
    const float* base = (ci < Ci1) ? in1 + ((size_t)b * Ci1 + ci) * in_sp
                                   : in2 + ((size_t)b * Ci2 + (ci - Ci1)) * in_sp;
    const float* wc = W + (size_t)ci * 81;
    for (int kt = 0; kt < 3; kt++) {
      int t = to * stride + kt - 1; if (t < 0 || t >= Ti) continue;
      for (int kx = 0; kx < 3; kx++) {
        int xx = xo * stride + kx - 1; if (xx < 0 || xx >= Xi) continue;
        for (int ky = 0; ky < 3; ky++) {
          int y = yo * stride + ky - 1; if (y < 0 || y >= Yi) continue;
          for (int kz = 0; kz < 3; kz++) {
            int z = zo * stride + kz - 1; if (z < 0 || z >= Zi) continue;
            float v = base[(((size_t)t * Xi + xx) * Yi + y) * Zi + z];
            int tap = ((kt * 3 + kx) * 3 + ky) * 3 + kz;
#pragma unroll
            for (int o = 0; o < 20; o++) acc[o] += v * wc[(size_t)o * Ci * 81 + tap];
          }
        }
      }
    }
  }
  size_t osp = (size_t)To * Xo * Yo * Zo;
  size_t obase = (size_t)b * 20 * osp + (((size_t)to * Xo + xo) * Yo + yo) * Zo + zo;
#pragma unroll
  for (int o = 0; o < 20; o++) out[obase + (size_t)o * osp] = acc[o];
}

__global__ void k_conv4d_elem(const float* __restrict__ in, const float* __restrict__ W,
                              float* __restrict__ out, int Ci,
                              int Ti, int Xi, int Yi, int Zi,
                              int To, int Xo, int Yo, int Zo, int stride, int n) {
  int idx = blockIdx.x * 256 + threadIdx.x;
  if (idx >= n) return;
  int zo = idx % Zo; int r = idx / Zo;
  int yo = r % Yo; r /= Yo;
  int xo = r % Xo; r /= Xo;
  int to = r % To; r /= To;
  int o = r % 20; int b = r / 20;
  float acc = 0.f;
  size_t in_sp = (size_t)Ti * Xi * Yi * Zi;
  for (int ci = 0; ci < Ci; ci++) {
    const float* base = in + ((size_t)b * Ci + ci) * in_sp;
    const float* wc = W + ((size_t)o * Ci + ci) * 81;
    for (int kt = 0; kt < 3; kt++) {
      int t = to * stride + kt - 1; if (t < 0 || t >= Ti) continue;
      for (int kx = 0; kx < 3; kx++) {
        int xx = xo * stride + kx - 1; if (xx < 0 || xx >= Xi) continue;
        for (int ky = 0; ky < 3; ky++) {
          int y = yo * stride + ky - 1; if (y < 0 || y >= Yi) continue;
          for (int kz = 0; kz < 3; kz++) {
            int z = zo * stride + kz - 1; if (z < 0 || z >= Zi) continue;
            acc += base[(((size_t)t * Xi + xx) * Yi + y) * Zi + z] * wc[((kt * 3 + kx) * 3 + ky) * 3 + kz];
          }
        }
      }
    }
  }
  out[idx] = acc;
}

// ---------------- BN ----------------
__global__ void k_bn_stats(const float* __restrict__ d, int S, float* __restrict__ stats) {
  int c = blockIdx.x;
  int tid = threadIdx.x;
  float s = 0.f, s2 = 0.f;
  for (int b = 0; b < 4; b++) {
    const float* p = d + ((size_t)b * 20 + c) * S;
    for (int i = tid; i < S; i += 256) { float v = p[i]; s += v; s2 += v * v; }
  }
  __shared__ float ls[256], lq[256];
  ls[tid] = s; lq[tid] = s2;
  __syncthreads();
  for (int off = 128; off > 0; off >>= 1) {
    if (tid < off) { ls[tid] += ls[tid + off]; lq[tid] += lq[tid + off]; }
    __syncthreads();
  }
  if (tid == 0) {
    float cnt = 4.f * (float)S;
    float mean = ls[0] / cnt;
    float var = lq[0] / cnt - mean * mean;
    stats[2 * c] = mean;
    stats[2 * c + 1] = rsqrtf(var + 1e-5f);
  }
}

__global__ void k_bn_apply(float* __restrict__ d, int S, const float* __restrict__ stats,
                           const float* __restrict__ g, const float* __restrict__ bb, int n) {
  int idx = blockIdx.x * 256 + threadIdx.x;
  if (idx >= n) return;
  int c = (idx / S) % 20;
  float v = d[idx];
  v = (v - stats[2 * c]) * stats[2 * c + 1] * g[c] + bb[c];
  d[idx] = (v >= 0.f) ? v : 0.1f * v;
}

// BN apply for oc1 + bf16 channels-last copy into CLd0 ci 0..19
// oc1: [b][c20][t8 x16 y16 z8]; CL row = pos*40 + c
__global__ void k_bn_apply_cl(float* __restrict__ d, const float* __restrict__ stats,
                              const float* __restrict__ g, const float* __restrict__ bb,
                              short* __restrict__ CL, int n) {
  int idx = blockIdx.x * 256 + threadIdx.x;
  if (idx >= n) return;
  int s = idx & 16383;
  int r = idx >> 14;
  int c = r % 20, b = r / 20;
  float v = d[idx];
  v = (v - stats[2 * c]) * stats[2 * c + 1] * g[c] + bb[c];
  v = (v >= 0.f) ? v : 0.1f * v;
  d[idx] = v;
  CL[((size_t)(b * 16384 + s)) * 40 + c] = f2bf(v);
}

// ---------------- deconv (ConvTranspose4d k=4 s=2 p=1), bias+lrelu fused ----------------
__device__ __forceinline__ int dcands(int p, int n_in, int* q, int* k) {
  int cnt = 0;
  int q0 = (p + 1) >> 1, k0 = p + 1 - 2 * q0;
  if (q0 >= 0 && q0 < n_in) { q[cnt] = q0; k[cnt] = k0; cnt++; }
  int q1 = q0 - 1, k1 = k0 + 2;
  if (q1 >= 0 && q1 < n_in) { q[cnt] = q1; k[cnt] = k1; cnt++; }
  return cnt;
}

__global__ void k_deconv4d(const float* __restrict__ in1, int Ci1,
                           const float* __restrict__ in2, int Ci2,
                           const float* __restrict__ W, const float* __restrict__ bias,
                           float* __restrict__ out,
                           int Ti, int Xi, int Yi, int Zi, int n) {
  int idx = blockIdx.x * 256 + threadIdx.x;
  if (idx >= n) return;
  int To = 2 * Ti, Xo = 2 * Xi, Yo = 2 * Yi, Zo = 2 * Zi;
  int zo = idx % Zo; int r = idx / Zo;
  int yo = r % Yo; r /= Yo;
  int xo = r % Xo; r /= Xo;
  int to = r % To; int b = r / To;
  int qt[2], kt[2], qx[2], kx[2], qy[2], ky[2], qz[2], kz[2];
  int nt = dcands(to, Ti, qt, kt), nx = dcands(xo, Xi, qx, kx);
  int ny = dcands(yo, Yi, qy, ky), nz = dcands(zo, Zi, qz, kz);
  float acc[20];
#pragma unroll
  for (int o = 0; o < 20; o++) acc[o] = 0.f;
  int Ci = Ci1 + Ci2;
  size_t in_sp = (size_t)Ti * Xi * Yi * Zi;
  for (int ci = 0; ci < Ci; ci++) {
    const float* base = (ci < Ci1) ? in1 + ((size_t)b * Ci1 + ci) * in_sp
                                   : in2 + ((size_t)b * Ci2 + (ci - Ci1)) * in_sp;
    const float* wc = W + (size_t)ci * 5120;  // [ci][o(20)][256]
    for (int it = 0; it < nt; it++)
      for (int ix = 0; ix < nx; ix++)
        for (int iy = 0; iy < ny; iy++)
          for (int iz = 0; iz < nz; iz++) {
            float v = base[(((size_t)qt[it] * Xi + qx[ix]) * Yi + qy[iy]) * Zi + qz[iz]];
            int tap = ((kt[it] * 4 + kx[ix]) * 4 + ky[iy]) * 4 + kz[iz];
#pragma unroll
            for (int o = 0; o < 20; o++) acc[o] += v * wc[o * 256 + tap];
          }
  }
  size_t osp = (size_t)To * Xo * Yo * Zo;
  size_t obase = (size_t)b * 20 * osp + (((size_t)to * Xo + xo) * Yo + yo) * Zo + zo;
#pragma unroll
  for (int o = 0; o < 20; o++) {
    float v2 = acc[o] + bias[o];
    out[obase + (size_t)o * osp] = (v2 >= 0.f) ? v2 : 0.1f * v2;
  }
}

// d1 deconv: in 4x8x8x4 (oc2|od2, Ci=40) -> out 8x16x16x8 written bf16 CL ci 20..39
__global__ void k_deconv_d1_cl(const float* __restrict__ in1, const float* __restrict__ in2,
                               const float* __restrict__ W, const float* __restrict__ bias,
                               short* __restrict__ CL, int n) {
  int idx = blockIdx.x * 256 + threadIdx.x;
  if (idx >= n) return;
  int zo = idx & 7; int r = idx >> 3;
  int yo = r & 15; r >>= 4;
  int xo = r & 15; r >>= 4;
  int to = r & 7; int b = r >> 3;
  int qt[2], kt[2], qx[2], kx[2], qy[2], ky[2], qz[2], kz[2];
  int nt = dcands(to, 4, qt, kt), nx = dcands(xo, 8, qx, kx);
  int ny = dcands(yo, 8, qy, ky), nz = dcands(zo, 4, qz, kz);
  float acc[20];
#pragma unroll
  for (int o = 0; o < 20; o++) acc[o] = 0.f;
  const size_t in_sp = 4 * 8 * 8 * 4;
  for (int ci = 0; ci < 40; ci++) {
    const float* base = (ci < 20) ? in1 + ((size_t)b * 20 + ci) * in_sp
                                  : in2 + ((size_t)b * 20 + (ci - 20)) * in_sp;
    const float* wc = W + (size_t)ci * 5120;
    for (int it = 0; it < nt; it++)
      for (int ix = 0; ix < nx; ix++)
        for (int iy = 0; iy < ny; iy++)
          for (int iz = 0; iz < nz; iz++) {
            float v = base[(((size_t)qt[it] * 8 + qx[ix]) * 8 + qy[iy]) * 4 + qz[iz]];
            int tap = ((kt[it] * 4 + kx[ix]) * 4 + ky[iy]) * 4 + kz[iz];
#pragma unroll
            for (int o = 0; o < 20; o++) acc[o] += v * wc[o * 256 + tap];
          }
  }
  size_t pos = (((size_t)b * 8 + to) * 16 + xo) * 16 * 8 + (size_t)yo * 8 + zo;
  short* dst = CL + pos * 40 + 20;
#pragma unroll
  for (int o = 0; o < 20; o++) {
    float v2 = acc[o] + bias[o];
    v2 = (v2 >= 0.f) ? v2 : 0.1f * v2;
    dst[o] = f2bf(v2);
  }
}

// fill Xcl ci 0..19 from x (fp32 [c][spatial] -> bf16 channels-last)
__global__ void k_xcl_x(const float* __restrict__ x, short* __restrict__ Xcl, int n) {
  int i = blockIdx.x * 256 + threadIdx.x;
  if (i >= n) return;
  int s = i & 262143, b = i >> 18;
  short* dst = Xcl + (size_t)i * 40;
  const float* src = x + (size_t)b * 20 * 262144 + s;
#pragma unroll
  for (int c = 0; c < 20; c++) dst[c] = f2bf(src[(size_t)c * 262144]);
}

// pack out_w [20][40][81] -> Wp[tap(81)][mt(2)][m(16)][k(64)] bf16 + zero-page
__global__ void k_pack_w(const float* __restrict__ out_w, short* __restrict__ Wp,
                         short* __restrict__ zp, int n) {
  int i = blockIdx.x * 256 + threadIdx.x;
  if (i >= n) return;
  int k = i & 63, m = (i >> 6) & 15, mt = (i >> 10) & 1, tap = i >> 11;
  int o = mt * 16 + m;
  float v = (o < 20 && k < 40) ? out_w[((size_t)o * 40 + k) * 81 + tap] : 0.f;
  Wp[i] = f2bf(v);
  if (i < 64) zp[i] = 0;
}

// pack d0_w [40][20][256] -> Wd[tap(256)][mt(2)][m(16)][k(64)] bf16
__global__ void k_pack_wd(const float* __restrict__ d0_w, short* __restrict__ Wd, int n) {
  int i = blockIdx.x * 256 + threadIdx.x;
  if (i >= n) return;
  int k = i & 63, m = (i >> 6) & 15, mt = (i >> 10) & 1, tap = i >> 11;
  int o = mt * 16 + m;
  float v = (o < 20 && k < 40) ? d0_w[((size_t)k * 20 + o) * 256 + tap] : 0.f;
  Wd[i] = f2bf(v);
}

// ---------------- d0 deconv via MFMA (parity-class decomposition) ----------------
// CL: [b4][t8][x16][y16][z8][ci40] bf16. Wd: [tap256][mt2][16][64] bf16.
// Output: Xcl ci 20..39, bias+lrelu fused. One wave per (b,ut,ux,uz); N=16 over uy.
__global__ __launch_bounds__(256) void k_d0_mfma(
    const short* __restrict__ CL, const short* __restrict__ Wd,
    const short* __restrict__ zp, const float* __restrict__ bias,
    short* __restrict__ Xcl) {
  int gw = blockIdx.x * 4 + (threadIdx.x >> 6);
  int uz = gw & 7, ux = (gw >> 3) & 15, ut = (gw >> 7) & 7, b = gw >> 10;
  int lane = threadIdx.x & 63;
  int ln15 = lane & 15, kg = lane >> 4;  // ln15 = uy

  const char* xb = (const char*)CL;
  const char* wb = (const char*)Wd;
  const char* zb = (const char*)zp;

#pragma unroll 1
  for (int cls = 0; cls < 16; cls++) {
    int et = (cls >> 3) & 1, ex = (cls >> 2) & 1, ey = (cls >> 1) & 1, ez = cls & 1;
    f32x4 acc0, acc1;
#pragma unroll
    for (int j = 0; j < 4; j++) { acc0[j] = 0.f; acc1[j] = 0.f; }
    // parity e: cand i: e==0 -> (k=1+2i, off=-i); e==1 -> (k=2i, off=1-i)
#pragma unroll
    for (int it = 0; it < 2; it++) {
      int kt = et ? (2 * it) : (1 + 2 * it);
      int qt = ut + (et ? (1 - it) : (-it));
      if (qt < 0 || qt > 7) continue;
#pragma unroll
      for (int ix = 0; ix < 2; ix++) {
        int kx = ex ? (2 * ix) : (1 + 2 * ix);
        int qx = ux + (ex ? (1 - ix) : (-ix));
        if (qx < 0 || qx > 15) continue;
#pragma unroll
        for (int iz = 0; iz < 2; iz++) {
          int kz = ez ? (2 * iz) : (1 + 2 * iz);
          int qz = uz + (ez ? (1 - iz) : (-iz));
          if (qz < 0 || qz > 7) continue;
#pragma unroll
          for (int iy = 0; iy < 2; iy++) {
            int ky = ey ? (2 * iy) : (1 + 2 * iy);
            int qy = ln15 + (ey ? (1 - iy) : (-iy));
            bool yok = (qy >= 0) && (qy < 16);
            int tap = ((kt * 4 + kx) * 4 + ky) * 4 + kz;
            long pos = ((((long)b * 8 + qt) * 16 + qx) * 16 + qy) * 8 + qz;
            const char* wt = wb + (size_t)tap * 4096;
#pragma unroll
            for (int ch = 0; ch < 2; ch++) {
              bf16x8 a0 = *(const bf16x8*)(wt + ln15 * 128 + ch * 64 + kg * 16);
              bf16x8 a1 = *(const bf16x8*)(wt + 2048 + ln15 * 128 + ch * 64 + kg * 16);
              const char* src = yok ? (xb + pos * 80 + ch * 64 + kg * 16)
                                    : (zb + ch * 64 + kg * 16);
              bf16x8 bv = *(const bf16x8*)src;
              acc0 = __builtin_amdgcn_mfma_f32_16x16x32_bf16(a0, bv, acc0, 0, 0, 0);
              acc1 = __builtin_amdgcn_mfma_f32_16x16x32_bf16(a1, bv, acc1, 0, 0, 0);
            }
          }
        }
      }
    }
    // epilogue: col=ln15=uy, row=kg*4+r = o (per mtile)
    int to = 2 * ut + et, xo = 2 * ux + ex, zo = 2 * uz + ez, yo = 2 * ln15 + ey;
    long opos = ((((long)b * 16 + to) * 32 + xo) * 32 + yo) * 16 + zo;
    short* dst = Xcl + opos * 40 + 20;
    {
      unsigned h[4];
#pragma unroll
      for (int r = 0; r < 4; r++) {
        float v = acc0[r] + bias[kg * 4 + r];
        v = (v >= 0.f) ? v : 0.1f * v;
        h[r] = (unsigned)(unsigned short)f2bf(v);
      }
      uint2 u;
      u.x = h[0] | (h[1] << 16);
      u.y = h[2] | (h[3] << 16);
      *(uint2*)(dst + kg * 4) = u;
    }
    if (kg == 0) {
      unsigned h[4];
#pragma unroll
      for (int r = 0; r < 4; r++) {
        float v = acc1[r] + bias[16 + r];
        v = (v >= 0.f) ? v : 0.1f * v;
        h[r] = (unsigned)(unsigned short)f2bf(v);
      }
      uint2 u;
      u.x = h[0] | (h[1] << 16);
      u.y = h[2] | (h[3] << 16);
      *(uint2*)(dst + 16) = u;
    }
  }
}

// ---------------- final conv: bf16 MFMA implicit GEMM ----------------
__global__ __launch_bounds__(256) void k_fconv_mfma(
    const short* __restrict__ Xcl, const short* __restrict__ Wp,
    const short* __restrict__ zp, const float* __restrict__ bias,
    float* __restrict__ io) {
  int bid = blockIdx.x;
  int yb = bid & 1, x0 = (bid >> 1) & 31, t0 = (bid >> 6) & 15, b = bid >> 10;
  int lane = threadIdx.x & 63, wave = threadIdx.x >> 6;
  int ln15 = lane & 15, kg = lane >> 4;
  int ybase = yb * 16 + wave * 4;

  f32x4 acc[2][4];
#pragma unroll
  for (int mt = 0; mt < 2; mt++)
#pragma unroll
    for (int nt = 0; nt < 4; nt++)
#pragma unroll
      for (int j = 0; j < 4; j++) acc[mt][nt][j] = 0.f;

  const char* xb = (const char*)Xcl;
  const char* wb = (const char*)Wp;
  const char* zb = (const char*)zp;

  for (int kt = 0; kt < 3; kt++) {
    int ti = t0 + kt - 1;
    if (ti < 0 || ti > 15) continue;
    for (int kx = 0; kx < 3; kx++) {
      int xi = x0 + kx - 1;
      if (xi < 0 || xi > 31) continue;
      long rowbase = ((long)((b * 16 + ti) * 32 + xi)) * 32;
      for (int ky = 0; ky < 3; ky++) {
#pragma unroll
        for (int kz = 0; kz < 3; kz++) {
          int tap = ((kt * 3 + kx) * 3 + ky) * 3 + kz;
          int zi = ln15 + kz - 1;
          bool zok = (zi >= 0) && (zi < 16);
          const char* wt = wb + (size_t)tap * 4096;
#pragma unroll
          for (int ch = 0; ch < 2; ch++) {
            bf16x8 a0 = *(const bf16x8*)(wt + ln15 * 128 + ch * 64 + kg * 16);
            bf16x8 a1 = *(const bf16x8*)(wt + 2048 + ln15 * 128 + ch * 64 + kg * 16);
#pragma unroll
            for (int nt = 0; nt < 4; nt++) {
              int yi = ybase + nt + ky - 1;
              if (yi < 0 || yi > 31) continue;
              long pos = (rowbase + yi) * 16 + (long)zi;
              const char* src = zok ? (xb + pos * 80 + ch * 64 + kg * 16)
                                    : (zb + ch * 64 + kg * 16);
              bf16x8 bv = *(const bf16x8*)src;
              acc[0][nt] = __builtin_amdgcn_mfma_f32_16x16x32_bf16(a0, bv, acc[0][nt], 0, 0, 0);
              acc[1][nt] = __builtin_amdgcn_mfma_f32_16x16x32_bf16(a1, bv, acc[1][nt], 0, 0, 0);
            }
          }
        }
      }
    }
  }

#pragma unroll
  for (int mt = 0; mt < 2; mt++)
#pragma unroll
    for (int r = 0; r < 4; r++) {
      int o = mt * 16 + kg * 4 + r;
      if (o >= 20) continue;
      float bo = bias[o];
#pragma unroll
      for (int nt = 0; nt < 4; nt++) {
        int y = ybase + nt;
        size_t oidx = ((size_t)(b * 20 + o)) * 262144 +
                      ((((size_t)t0 * 32 + x0) * 32 + y) * 16 + ln15);
        float v = acc[mt][nt][r] + bo + io[oidx];
        io[oidx] = fmaxf(v, 0.f);
      }
    }
}

extern "C" void kernel_launch(void* const* d_in, const int* in_sizes, int n_in,
                              void* d_out, int out_size, void* d_ws, size_t ws_size,
                              hipStream_t stream) {
  const float* x     = (const float*)d_in[0];
  const float* sw1   = (const float*)d_in[1];
  const float* sw2   = (const float*)d_in[2];
  const float* sw3   = (const float*)d_in[3];
  const float* sw4   = (const float*)d_in[4];
  const float* w_pw  = (const float*)d_in[5];
  const float* b_pw  = (const float*)d_in[6];
  const float* c1_w  = (const float*)d_in[7];
  const float* c2_w  = (const float*)d_in[8];
  const float* c21_w = (const float*)d_in[9];
  const float* c3_w  = (const float*)d_in[10];
  const float* c31_w = (const float*)d_in[11];
  const float* bn1_g = (const float*)d_in[12];
  const float* bn1_b = (const float*)d_in[13];
  const float* bn2_g = (const float*)d_in[14];
  const float* bn2_b = (const float*)d_in[15];
  const float* bn21_g = (const float*)d_in[16];
  const float* bn21_b = (const float*)d_in[17];
  const float* bn3_g = (const float*)d_in[18];
  const float* bn3_b = (const float*)d_in[19];
  const float* bn31_g = (const float*)d_in[20];
  const float* bn31_b = (const float*)d_in[21];
  const float* d2_w  = (const float*)d_in[22];
  const float* d2_b  = (const float*)d_in[23];
  const float* d1_w  = (const float*)d_in[24];
  const float* d1_b  = (const float*)d_in[25];
  const float* d0_w  = (const float*)d_in[26];
  const float* d0_b  = (const float*)d_in[27];
  const float* out_w = (const float*)d_in[28];
  const float* out_b = (const float*)d_in[29];
  float* out = (float*)d_out;
  float* ws = (float*)d_ws;

  // spectral arena (phase 1 only; fully dead before U-Net writes anything)
  float2* A  = (float2*)(ws);
  float2* Bb = (float2*)(ws + 10485760);
  float2* Cb = (float2*)(ws + 13107200);
  float2* Dd = (float2*)(ws + 14417920);
  float2* Ee = (float2*)(ws + 15073280);
  float2* Ff = (float2*)(ws + 15728640);
  float2* Gg = (float2*)(ws + 16384000);

  // U-Net arena (float offsets)
  float* oc1   = ws;                       // 0 .. 1,310,720 (dead after c2 conv)
  short* CLd0  = (short*)(ws + 1310720);   // 1,310,720 .. 2,621,440 (65536 pos x 40 bf16)
  float* oc2a  = ws + 2621440;             // 81,920
  float* oc2   = ws + 2703360;             // 81,920
  float* oc3a  = ws + 2785280;             // 5,120
  float* oc3   = ws + 2790400;             // 5,120
  float* od2   = ws + 2795520;             // 81,920 -> ends 2,877,440
  short* Xcl   = (short*)(ws + 2877440);   // 41,943,040 bf16 -> ends 23,848,960
  float* stats = ws + 23848960;            // 40
  // weight packs overlay dead oc1 (after c2 conv)
  short* Wd = (short*)(ws);                // 524,288 bf16 = 262,144 fl
  short* Wp = (short*)(ws + 262144);       // 165,888 bf16
  short* zp = (short*)(ws + 345088);       // 64 bf16

  auto nb = [](int n) { return (n + 255) / 256; };
  dim3 blk(256);

  // ---- spectral path: x1 -> d_out ----
  k_fwd_z<<<nb(1310720), blk, 0, stream>>>(x, A, 1310720);
  k_fwd_y<<<nb(1310720), blk, 0, stream>>>(A, Bb, 1310720);
  k_fwd_x<<<nb(655360), blk, 0, stream>>>(Bb, Cb, 655360);
  k_fwd_t<<<nb(327680), blk, 0, stream>>>(Cb, Dd, 327680);
  k_fwd_c<<<nb(327680), blk, 0, stream>>>(Dd, Ee, 327680);
  k_fwd_b<<<nb(327680), blk, 0, stream>>>(Ee, Ff, 327680);
  k_smul<<<nb(327680), blk, 0, stream>>>(Ff, sw1, sw2, sw3, sw4, Gg, 327680);
  k_inv_t<<<nb(655360), blk, 0, stream>>>(Gg, Cb, 655360);
  k_inv_x<<<nb(1310720), blk, 0, stream>>>(Cb, Bb, 1310720);
  k_inv_y<<<nb(5242880), blk, 0, stream>>>(Bb, A, 5242880);
  k_inv_z<<<nb(20971520), blk, 0, stream>>>(A, out, 20971520);

  // ---- pointwise path: += x2 ----
  k_x2<<<nb(1048576), blk, 0, stream>>>(x, w_pw, b_pw, out, 1048576);

  // ---- Xcl ci 0..19 from x ----
  k_xcl_x<<<nb(1048576), blk, 0, stream>>>(x, Xcl, 1048576);

  // ---- U-Net encoder ----
  k_conv4d_pos<<<nb(65536), blk, 0, stream>>>(x, 20, nullptr, 0, c1_w, oc1,
                                              16, 32, 32, 16, 8, 16, 16, 8, 2, 65536);
  k_bn_stats<<<20, blk, 0, stream>>>(oc1, 16384, stats);
  k_bn_apply_cl<<<nb(1310720), blk, 0, stream>>>(oc1, stats, bn1_g, bn1_b, CLd0, 1310720);

  k_conv4d_elem<<<nb(81920), blk, 0, stream>>>(oc1, c2_w, oc2a, 20,
                                               8, 16, 16, 8, 4, 8, 8, 4, 2, 81920);
  k_bn_stats<<<20, blk, 0, stream>>>(oc2a, 1024, stats);
  k_bn_apply<<<nb(81920), blk, 0, stream>>>(oc2a, 1024, stats, bn2_g, bn2_b, 81920);

  k_conv4d_elem<<<nb(81920), blk, 0, stream>>>(oc2a, c21_w, oc2, 20,
                                               4, 8, 8, 4, 4, 8, 8, 4, 1, 81920);
  k_bn_stats<<<20, blk, 0, stream>>>(oc2, 1024, stats);
  k_bn_apply<<<nb(81920), blk, 0, stream>>>(oc2, 1024, stats, bn21_g, bn21_b, 81920);

  k_conv4d_elem<<<nb(5120), blk, 0, stream>>>(oc2, c3_w, oc3a, 20,
                                              4, 8, 8, 4, 2, 4, 4, 2, 2, 5120);
  k_bn_stats<<<20, blk, 0, stream>>>(oc3a, 64, stats);
  k_bn_apply<<<nb(5120), blk, 0, stream>>>(oc3a, 64, stats, bn3_g, bn3_b, 5120);

  k_conv4d_elem<<<nb(5120), blk, 0, stream>>>(oc3a, c31_w, oc3, 20,
                                              2, 4, 4, 2, 2, 4, 4, 2, 1, 5120);
  k_bn_stats<<<20, blk, 0, stream>>>(oc3, 64, stats);
  k_bn_apply<<<nb(5120), blk, 0, stream>>>(oc3, 64, stats, bn31_g, bn31_b, 5120);

  // ---- decoder ----
  k_deconv4d<<<nb(4096), blk, 0, stream>>>(oc3, 20, nullptr, 0, d2_w, d2_b, od2,
                                           2, 4, 4, 2, 4096);
  k_deconv_d1_cl<<<nb(65536), blk, 0, stream>>>(oc2, od2, d1_w, d1_b, CLd0, 65536);

  // weight packs (oc1 is dead now)
  k_pack_w<<<nb(165888), blk, 0, stream>>>(out_w, Wp, zp, 165888);
  k_pack_wd<<<nb(524288), blk, 0, stream>>>(d0_w, Wd, 524288);

  // d0 deconv via MFMA -> Xcl ci 20..39
  k_d0_mfma<<<1024, blk, 0, stream>>>(CLd0, Wd, zp, d0_b, Xcl);

  // final conv via MFMA, fused +bias +x1+x2 +relu into d_out
  k_fconv_mfma<<<4096, blk, 0, stream>>>(Xcl, Wp, zp, out_b, out);
}

// Round 4
// 3471.389 us; speedup vs baseline: 2.6821x; 1.0672x over previous
//
#include <hip/hip_runtime.h>

#define PI2 6.28318530717958647692f

typedef __attribute__((ext_vector_type(8))) short bf16x8;
typedef __attribute__((ext_vector_type(4))) float f32x4;

__device__ __forceinline__ void cfma(float2& acc, float2 a, float2 b) {
  acc.x += a.x * b.x - a.y * b.y;
  acc.y += a.x * b.y + a.y * b.x;
}

__device__ __forceinline__ float2 twf(int m, float invN, float sign) {
  float a = sign * PI2 * (float)m * invN;
  float s, c;
  __sincosf(a, &s, &c);
  return make_float2(c, s);
}

__device__ __forceinline__ short f2bf(float f) {
  unsigned u = __float_as_uint(f);
  unsigned r = (u + 0x7fff + ((u >> 16) & 1)) >> 16;
  return (short)r;
}

// ---------------- spectral forward ----------------
__global__ void k_fwd_z(const float* __restrict__ x, float2* __restrict__ out, int nrows) {
  int r = blockIdx.x * 256 + threadIdx.x;
  if (r >= nrows) return;
  const float* p = x + (size_t)r * 16;
  float v[16];
#pragma unroll
  for (int z = 0; z < 16; z++) v[z] = p[z];
#pragma unroll
  for (int zk = 0; zk < 4; zk++) {
    float re = 0.f, im = 0.f;
#pragma unroll
    for (int z = 0; z < 16; z++) {
      float2 t = twf((z * zk) & 15, 1.f / 16.f, -1.f);
      re += v[z] * t.x;
      im += v[z] * t.y;
    }
    out[(size_t)r * 4 + zk] = make_float2(re, im);
  }
}

__global__ void k_fwd_y(const float2* __restrict__ in, float2* __restrict__ out, int n) {
  int i = blockIdx.x * 256 + threadIdx.x;
  if (i >= n) return;
  int zk = i & 3, yk = (i >> 2) & 7, slab = i >> 5;
  const float2* p = in + (size_t)slab * 128 + zk;
  float2 acc = make_float2(0.f, 0.f);
  for (int y = 0; y < 32; y++) cfma(acc, p[y * 4], twf((y * yk) & 31, 1.f / 32.f, -1.f));
  out[i] = acc;
}

__global__ void k_fwd_x(const float2* __restrict__ in, float2* __restrict__ out, int n) {
  int i = blockIdx.x * 256 + threadIdx.x;
  if (i >= n) return;
  int zk = i & 3, yk = (i >> 2) & 7, xi = (i >> 5) & 15, slab = i >> 9;
  int xk = (xi < 8) ? xi : xi + 16;
  const float2* p = in + (size_t)slab * 1024 + yk * 4 + zk;
  float2 acc = make_float2(0.f, 0.f);
  for (int xx = 0; xx < 32; xx++) cfma(acc, p[xx * 32], twf((xx * xk) & 31, 1.f / 32.f, -1.f));
  out[i] = acc;
}

__global__ void k_fwd_t(const float2* __restrict__ in, float2* __restrict__ out, int n) {
  int i = blockIdx.x * 256 + threadIdx.x;
  if (i >= n) return;
  int zk = i & 3, yk = (i >> 2) & 7, xi = (i >> 5) & 15, ti = (i >> 9) & 7, bc = i >> 12;
  int tk = (ti < 4) ? ti : ti + 8;
  const float2* p = in + (size_t)bc * 8192 + xi * 32 + yk * 4 + zk;
  float2 acc = make_float2(0.f, 0.f);
  for (int t = 0; t < 16; t++) cfma(acc, p[t * 512], twf((t * tk) & 15, 1.f / 16.f, -1.f));
  out[i] = acc;
}

__global__ void k_fwd_c(const float2* __restrict__ in, float2* __restrict__ out, int n) {
  int i = blockIdx.x * 256 + threadIdx.x;
  if (i >= n) return;
  int mode = i & 4095, r = i >> 12, ck = r % 20, b = r / 20;
  const float2* p = in + (size_t)b * 81920 + mode;
  float2 acc = make_float2(0.f, 0.f);
  for (int c = 0; c < 20; c++) cfma(acc, p[(size_t)c * 4096], twf((c * ck) % 20, 1.f / 20.f, -1.f));
  out[i] = acc;
}

__global__ void k_fwd_b(const float2* __restrict__ in, float2* __restrict__ out, int n) {
  int i = blockIdx.x * 256 + threadIdx.x;
  if (i >= n) return;
  int mode = i & 4095, r = i >> 12, ck = r % 20, bk = r / 20;
  const float2* p = in + (size_t)ck * 4096 + mode;
  float2 acc = make_float2(0.f, 0.f);
  for (int b = 0; b < 4; b++) cfma(acc, p[(size_t)b * 81920], twf((b * bk) & 3, 0.25f, -1.f));
  out[i] = acc;
}

__global__ void k_smul(const float2* __restrict__ in,
                       const float* __restrict__ sw1, const float* __restrict__ sw2,
                       const float* __restrict__ sw3, const float* __restrict__ sw4,
                       float2* __restrict__ out, int n) {
  int i = blockIdx.x * 256 + threadIdx.x;
  if (i >= n) return;
  int mode = i & 4095, r = i >> 12, o = r % 20, bk = r / 20;
  int ti = mode >> 9, xi = (mode >> 5) & 15, yk = (mode >> 2) & 7, zk = mode & 3;
  const float* w = (ti < 4) ? ((xi < 8) ? sw1 : sw3) : ((xi < 8) ? sw2 : sw4);
  int tl = ti & 3, xl = xi & 7;
  const float2* wp = (const float2*)w;
  const float2* ip = in + (size_t)bk * 81920 + mode;
  size_t wsub = (size_t)o * 1024 + (size_t)tl * 256 + (size_t)xl * 32 + yk * 4 + zk;
  float2 acc = make_float2(0.f, 0.f);
  for (int ci = 0; ci < 20; ci++) cfma(acc, ip[(size_t)ci * 4096], wp[(size_t)ci * 20480 + wsub]);
  out[i] = acc;
}

// ---------------- spectral inverse ----------------
__global__ void k_inv_t(const float2* __restrict__ in, float2* __restrict__ out, int n) {
  int i = blockIdx.x * 256 + threadIdx.x;
  if (i >= n) return;
  int zk = i & 3, yk = (i >> 2) & 7, xi = (i >> 5) & 15, tp = (i >> 9) & 15, bc = i >> 13;
  const float2* p = in + (size_t)bc * 4096 + xi * 32 + yk * 4 + zk;
  float2 acc = make_float2(0.f, 0.f);
  for (int ti = 0; ti < 8; ti++) {
    int tk = (ti < 4) ? ti : ti + 8;
    cfma(acc, p[ti * 512], twf((tk * tp) & 15, 1.f / 16.f, 1.f));
  }
  out[i] = acc;
}

__global__ void k_inv_x(const float2* __restrict__ in, float2* __restrict__ out, int n) {
  int i = blockIdx.x * 256 + threadIdx.x;
  if (i >= n) return;
  int zk = i & 3, yk = (i >> 2) & 7, xp = (i >> 5) & 31, tp = (i >> 10) & 15, bc = i >> 14;
  const float2* p = in + (size_t)bc * 8192 + tp * 512 + yk * 4 + zk;
  float2 acc = make_float2(0.f, 0.f);
  for (int xi = 0; xi < 16; xi++) {
    int xk = (xi < 8) ? xi : xi + 16;
    cfma(acc, p[xi * 32], twf((xk * xp) & 31, 1.f / 32.f, 1.f));
  }
  out[i] = acc;
}

__global__ void k_inv_y(const float2* __restrict__ in, float2* __restrict__ out, int n) {
  int i = blockIdx.x * 256 + threadIdx.x;
  if (i >= n) return;
  int zk = i & 3, yp = (i >> 2) & 31, xp = (i >> 7) & 31, tp = (i >> 12) & 15, bc = i >> 16;
  const float2* p = in + (size_t)bc * 16384 + tp * 1024 + xp * 32 + zk;
  float2 acc = make_float2(0.f, 0.f);
  for (int yk = 0; yk < 8; yk++) cfma(acc, p[yk * 4], twf((yk * yp) & 31, 1.f / 32.f, 1.f));
  out[i] = acc;
}

__global__ void k_inv_z(const float2* __restrict__ in, float* __restrict__ out, int n) {
  int i = blockIdx.x * 256 + threadIdx.x;
  if (i >= n) return;
  int zp = i & 15, row = i >> 4;
  const float2* p = in + (size_t)row * 4;
  float val = p[0].x;
#pragma unroll
  for (int zk = 1; zk < 4; zk++) {
    float2 t = twf((zk * zp) & 15, 1.f / 16.f, 1.f);
    val += 2.f * (p[zk].x * t.x - p[zk].y * t.y);
  }
  out[i] = val * (1.f / 262144.f);
}

// ---------------- pointwise path (adds into d_out) ----------------
__global__ void k_x2(const float* __restrict__ x, const float* __restrict__ w,
                     const float* __restrict__ bias, float* __restrict__ out, int n) {
  int i = blockIdx.x * 256 + threadIdx.x;
  if (i >= n) return;
  int s = i & 262143, b = i >> 18;
  float xv[20];
#pragma unroll
  for (int c = 0; c < 20; c++) xv[c] = x[((size_t)b * 20 + c) * 262144 + s];
#pragma unroll
  for (int o = 0; o < 20; o++) {
    float a = bias[o];
#pragma unroll
    for (int c = 0; c < 20; c++) a += w[o * 20 + c] * xv[c];
    out[((size_t)b * 20 + o) * 262144 + s] += a;
  }
}

// ---------------- U-Net: convs ----------------
__global__ void k_conv4d_pos(const float* __restrict__ in1, int Ci1,
                             const float* __restrict__ in2, int Ci2,
                             const float* __restrict__ W, float* __restrict__ out,
                             int Ti, int Xi, int Yi, int Zi,
                             int To, int Xo, int Yo, int Zo, int stride, int n) {
  int idx = blockIdx.x * 256 + threadIdx.x;
  if (idx >= n) return;
  int zo = idx % Zo; int r = idx / Zo;
  int yo = r % Yo; r /= Yo;
  int xo = r % Xo; r /= Xo;
  int to = r % To; int b = r / To;
  float acc[20];
#pragma unroll
  for (int o = 0; o < 20; o++) acc[o] = 0.f;
  int Ci = Ci1 + Ci2;
  size_t in_sp = (size_t)Ti * Xi * Yi * Zi;
  for (int ci = 0; ci < Ci; ci++) {
    const float* base = (ci < Ci1) ? in1 + ((size_t)b * Ci1 + ci) * in_sp
                                   : in2 + ((size_t)b * Ci2 + (ci - Ci1)) * in_sp;
    const float* wc = W + (size_t)ci * 81;
    for (int kt = 0; kt < 3; kt++) {
      int t = to * stride + kt - 1; if (t < 0 || t >= Ti) continue;
      for (int kx = 0; kx < 3; kx++) {
        int xx = xo * stride + kx - 1; if (xx < 0 || xx >= Xi) continue;
        for (int ky = 0; ky < 3; ky++) {
          int y = yo * stride + ky - 1; if (y < 0 || y >= Yi) continue;
          for (int kz = 0; kz < 3; kz++) {
            int z = zo * stride + kz - 1; if (z < 0 || z >= Zi) continue;
            float v = base[(((size_t)t * Xi + xx) * Yi + y) * Zi + z];
            int tap = ((kt * 3 + kx) * 3 + ky) * 3 + kz;
#pragma unroll
            for (int o = 0; o < 20; o++) acc[o] += v * wc[(size_t)o * Ci * 81 + tap];
          }
        }
      }
    }
  }
  size_t osp = (size_t)To * Xo * Yo * Zo;
  size_t obase = (size_t)b * 20 * osp + (((size_t)to * Xo + xo) * Yo + yo) * Zo + zo;
#pragma unroll
  for (int o = 0; o < 20; o++) out[obase + (size_t)o * osp] = acc[o];
}

__global__ void k_conv4d_elem(const float* __restrict__ in, const float* __restrict__ W,
                              float* __restrict__ out, int Ci,
                              int Ti, int Xi, int Yi, int Zi,
                              int To, int Xo, int Yo, int Zo, int stride, int n) {
  int idx = blockIdx.x * 256 + threadIdx.x;
  if (idx >= n) return;
  int zo = idx % Zo; int r = idx / Zo;
  int yo = r % Yo; r /= Yo;
  int xo = r % Xo; r /= Xo;
  int to = r % To; r /= To;
  int o = r % 20; int b = r / 20;
  float acc = 0.f;
  size_t in_sp = (size_t)Ti * Xi * Yi * Zi;
  for (int ci = 0; ci < Ci; ci++) {
    const float* base = in + ((size_t)b * Ci + ci) * in_sp;
    const float* wc = W + ((size_t)o * Ci + ci) * 81;
    for (int kt = 0; kt < 3; kt++) {
      int t = to * stride + kt - 1; if (t < 0 || t >= Ti) continue;
      for (int kx = 0; kx < 3; kx++) {
        int xx = xo * stride + kx - 1; if (xx < 0 || xx >= Xi) continue;
        for (int ky = 0; ky < 3; ky++) {
          int y = yo * stride + ky - 1; if (y < 0 || y >= Yi) continue;
          for (int kz = 0; kz < 3; kz++) {
            int z = zo * stride + kz - 1; if (z < 0 || z >= Zi) continue;
            acc += base[(((size_t)t * Xi + xx) * Yi + y) * Zi + z] * wc[((kt * 3 + kx) * 3 + ky) * 3 + kz];
          }
        }
      }
    }
  }
  out[idx] = acc;
}

// ---------------- BN ----------------
__global__ void k_bn_stats(const float* __restrict__ d, int S, float* __restrict__ stats) {
  int c = blockIdx.x;
  int tid = threadIdx.x;
  float s = 0.f, s2 = 0.f;
  for (int b = 0; b < 4; b++) {
    const float* p = d + ((size_t)b * 20 + c) * S;
    for (int i = tid; i < S; i += 256) { float v = p[i]; s += v; s2 += v * v; }
  }
  __shared__ float ls[256], lq[256];
  ls[tid] = s; lq[tid] = s2;
  __syncthreads();
  for (int off = 128; off > 0; off >>= 1) {
    if (tid < off) { ls[tid] += ls[tid + off]; lq[tid] += lq[tid + off]; }
    __syncthreads();
  }
  if (tid == 0) {
    float cnt = 4.f * (float)S;
    float mean = ls[0] / cnt;
    float var = lq[0] / cnt - mean * mean;
    stats[2 * c] = mean;
    stats[2 * c + 1] = rsqrtf(var + 1e-5f);
  }
}

__global__ void k_bn_apply(float* __restrict__ d, int S, const float* __restrict__ stats,
                           const float* __restrict__ g, const float* __restrict__ bb, int n) {
  int idx = blockIdx.x * 256 + threadIdx.x;
  if (idx >= n) return;
  int c = (idx / S) % 20;
  float v = d[idx];
  v = (v - stats[2 * c]) * stats[2 * c + 1] * g[c] + bb[c];
  d[idx] = (v >= 0.f) ? v : 0.1f * v;
}

// BN apply for oc1 + bf16 channels-last copy into CLd0 ci 0..19
__global__ void k_bn_apply_cl(float* __restrict__ d, const float* __restrict__ stats,
                              const float* __restrict__ g, const float* __restrict__ bb,
                              short* __restrict__ CL, int n) {
  int idx = blockIdx.x * 256 + threadIdx.x;
  if (idx >= n) return;
  int s = idx & 16383;
  int r = idx >> 14;
  int c = r % 20, b = r / 20;
  float v = d[idx];
  v = (v - stats[2 * c]) * stats[2 * c + 1] * g[c] + bb[c];
  v = (v >= 0.f) ? v : 0.1f * v;
  d[idx] = v;
  CL[((size_t)(b * 16384 + s)) * 40 + c] = f2bf(v);
}

// ---------------- deconv (ConvTranspose4d k=4 s=2 p=1), bias+lrelu fused ----------------
__device__ __forceinline__ int dcands(int p, int n_in, int* q, int* k) {
  int cnt = 0;
  int q0 = (p + 1) >> 1, k0 = p + 1 - 2 * q0;
  if (q0 >= 0 && q0 < n_in) { q[cnt] = q0; k[cnt] = k0; cnt++; }
  int q1 = q0 - 1, k1 = k0 + 2;
  if (q1 >= 0 && q1 < n_in) { q[cnt] = q1; k[cnt] = k1; cnt++; }
  return cnt;
}

__global__ void k_deconv4d(const float* __restrict__ in1, int Ci1,
                           const float* __restrict__ in2, int Ci2,
                           const float* __restrict__ W, const float* __restrict__ bias,
                           float* __restrict__ out,
                           int Ti, int Xi, int Yi, int Zi, int n) {
  int idx = blockIdx.x * 256 + threadIdx.x;
  if (idx >= n) return;
  int To = 2 * Ti, Xo = 2 * Xi, Yo = 2 * Yi, Zo = 2 * Zi;
  int zo = idx % Zo; int r = idx / Zo;
  int yo = r % Yo; r /= Yo;
  int xo = r % Xo; r /= Xo;
  int to = r % To; int b = r / To;
  int qt[2], kt[2], qx[2], kx[2], qy[2], ky[2], qz[2], kz[2];
  int nt = dcands(to, Ti, qt, kt), nx = dcands(xo, Xi, qx, kx);
  int ny = dcands(yo, Yi, qy, ky), nz = dcands(zo, Zi, qz, kz);
  float acc[20];
#pragma unroll
  for (int o = 0; o < 20; o++) acc[o] = 0.f;
  int Ci = Ci1 + Ci2;
  size_t in_sp = (size_t)Ti * Xi * Yi * Zi;
  for (int ci = 0; ci < Ci; ci++) {
    const float* base = (ci < Ci1) ? in1 + ((size_t)b * Ci1 + ci) * in_sp
                                   : in2 + ((size_t)b * Ci2 + (ci - Ci1)) * in_sp;
    const float* wc = W + (size_t)ci * 5120;  // [ci][o(20)][256]
    for (int it = 0; it < nt; it++)
      for (int ix = 0; ix < nx; ix++)
        for (int iy = 0; iy < ny; iy++)
          for (int iz = 0; iz < nz; iz++) {
            float v = base[(((size_t)qt[it] * Xi + qx[ix]) * Yi + qy[iy]) * Zi + qz[iz]];
            int tap = ((kt[it] * 4 + kx[ix]) * 4 + ky[iy]) * 4 + kz[iz];
#pragma unroll
            for (int o = 0; o < 20; o++) acc[o] += v * wc[o * 256 + tap];
          }
  }
  size_t osp = (size_t)To * Xo * Yo * Zo;
  size_t obase = (size_t)b * 20 * osp + (((size_t)to * Xo + xo) * Yo + yo) * Zo + zo;
#pragma unroll
  for (int o = 0; o < 20; o++) {
    float v2 = acc[o] + bias[o];
    out[obase + (size_t)o * osp] = (v2 >= 0.f) ? v2 : 0.1f * v2;
  }
}

// d1 deconv: in 4x8x8x4 (oc2|od2, Ci=40) -> out 8x16x16x8 written bf16 CL ci 20..39
__global__ void k_deconv_d1_cl(const float* __restrict__ in1, const float* __restrict__ in2,
                               const float* __restrict__ W, const float* __restrict__ bias,
                               short* __restrict__ CL, int n) {
  int idx = blockIdx.x * 256 + threadIdx.x;
  if (idx >= n) return;
  int zo = idx & 7; int r = idx >> 3;
  int yo = r & 15; r >>= 4;
  int xo = r & 15; r >>= 4;
  int to = r & 7; int b = r >> 3;
  int qt[2], kt[2], qx[2], kx[2], qy[2], ky[2], qz[2], kz[2];
  int nt = dcands(to, 4, qt, kt), nx = dcands(xo, 8, qx, kx);
  int ny = dcands(yo, 8, qy, ky), nz = dcands(zo, 4, qz, kz);
  float acc[20];
#pragma unroll
  for (int o = 0; o < 20; o++) acc[o] = 0.f;
  const size_t in_sp = 4 * 8 * 8 * 4;
  for (int ci = 0; ci < 40; ci++) {
    const float* base = (ci < 20) ? in1 + ((size_t)b * 20 + ci) * in_sp
                                  : in2 + ((size_t)b * 20 + (ci - 20)) * in_sp;
    const float* wc = W + (size_t)ci * 5120;
    for (int it = 0; it < nt; it++)
      for (int ix = 0; ix < nx; ix++)
        for (int iy = 0; iy < ny; iy++)
          for (int iz = 0; iz < nz; iz++) {
            float v = base[(((size_t)qt[it] * 8 + qx[ix]) * 8 + qy[iy]) * 4 + qz[iz]];
            int tap = ((kt[it] * 4 + kx[ix]) * 4 + ky[iy]) * 4 + kz[iz];
#pragma unroll
            for (int o = 0; o < 20; o++) acc[o] += v * wc[o * 256 + tap];
          }
  }
  size_t pos = (((size_t)b * 8 + to) * 16 + xo) * 16 * 8 + (size_t)yo * 8 + zo;
  short* dst = CL + pos * 40 + 20;
#pragma unroll
  for (int o = 0; o < 20; o++) {
    float v2 = acc[o] + bias[o];
    v2 = (v2 >= 0.f) ? v2 : 0.1f * v2;
    dst[o] = f2bf(v2);
  }
}

// fill Xcl ci 0..19 from x
__global__ void k_xcl_x(const float* __restrict__ x, short* __restrict__ Xcl, int n) {
  int i = blockIdx.x * 256 + threadIdx.x;
  if (i >= n) return;
  int s = i & 262143, b = i >> 18;
  short* dst = Xcl + (size_t)i * 40;
  const float* src = x + (size_t)b * 20 * 262144 + s;
#pragma unroll
  for (int c = 0; c < 20; c++) dst[c] = f2bf(src[(size_t)c * 262144]);
}

// pack out_w [20][40][81] -> Wp[tap(81)][mt(2)][m(16)][k(64)] bf16 + zero-page
__global__ void k_pack_w(const float* __restrict__ out_w, short* __restrict__ Wp,
                         short* __restrict__ zp, int n) {
  int i = blockIdx.x * 256 + threadIdx.x;
  if (i >= n) return;
  int k = i & 63, m = (i >> 6) & 15, mt = (i >> 10) & 1, tap = i >> 11;
  int o = mt * 16 + m;
  float v = (o < 20 && k < 40) ? out_w[((size_t)o * 40 + k) * 81 + tap] : 0.f;
  Wp[i] = f2bf(v);
  if (i < 64) zp[i] = 0;
}

// pack d0_w [40][20][256] -> Wd[tap(256)][mt(2)][m(16)][k(64)] bf16
__global__ void k_pack_wd(const float* __restrict__ d0_w, short* __restrict__ Wd, int n) {
  int i = blockIdx.x * 256 + threadIdx.x;
  if (i >= n) return;
  int k = i & 63, m = (i >> 6) & 15, mt = (i >> 10) & 1, tap = i >> 11;
  int o = mt * 16 + m;
  float v = (o < 20 && k < 40) ? d0_w[((size_t)k * 20 + o) * 256 + tap] : 0.f;
  Wd[i] = f2bf(v);
}

// ---------------- d0 deconv via MFMA (parity-class decomposition) ----------------
__global__ __launch_bounds__(256) void k_d0_mfma(
    const short* __restrict__ CL, const short* __restrict__ Wd,
    const short* __restrict__ zp, const float* __restrict__ bias,
    short* __restrict__ Xcl) {
  int gw = blockIdx.x * 4 + (threadIdx.x >> 6);
  int uz = gw & 7, ux = (gw >> 3) & 15, ut = (gw >> 7) & 7, b = gw >> 10;
  int lane = threadIdx.x & 63;
  int ln15 = lane & 15, kg = lane >> 4;  // ln15 = uy

  const char* xb = (const char*)CL;
  const char* wb = (const char*)Wd;
  const char* zb = (const char*)zp;

#pragma unroll 1
  for (int cls = 0; cls < 16; cls++) {
    int et = (cls >> 3) & 1, ex = (cls >> 2) & 1, ey = (cls >> 1) & 1, ez = cls & 1;
    f32x4 acc0, acc1;
#pragma unroll
    for (int j = 0; j < 4; j++) { acc0[j] = 0.f; acc1[j] = 0.f; }
#pragma unroll
    for (int it = 0; it < 2; it++) {
      int kt = et ? (2 * it) : (1 + 2 * it);
      int qt = ut + (et ? (1 - it) : (-it));
      if (qt < 0 || qt > 7) continue;
#pragma unroll
      for (int ix = 0; ix < 2; ix++) {
        int kx = ex ? (2 * ix) : (1 + 2 * ix);
        int qx = ux + (ex ? (1 - ix) : (-ix));
        if (qx < 0 || qx > 15) continue;
#pragma unroll
        for (int iz = 0; iz < 2; iz++) {
          int kz = ez ? (2 * iz) : (1 + 2 * iz);
          int qz = uz + (ez ? (1 - iz) : (-iz));
          if (qz < 0 || qz > 7) continue;
#pragma unroll
          for (int iy = 0; iy < 2; iy++) {
            int ky = ey ? (2 * iy) : (1 + 2 * iy);
            int qy = ln15 + (ey ? (1 - iy) : (-iy));
            bool yok = (qy >= 0) && (qy < 16);
            int tap = ((kt * 4 + kx) * 4 + ky) * 4 + kz;
            long pos = ((((long)b * 8 + qt) * 16 + qx) * 16 + qy) * 8 + qz;
            const char* wt = wb + (size_t)tap * 4096;
#pragma unroll
            for (int ch = 0; ch < 2; ch++) {
              bf16x8 a0 = *(const bf16x8*)(wt + ln15 * 128 + ch * 64 + kg * 16);
              bf16x8 a1 = *(const bf16x8*)(wt + 2048 + ln15 * 128 + ch * 64 + kg * 16);
              const char* src = yok ? (xb + pos * 80 + ch * 64 + kg * 16)
                                    : (zb + ch * 64 + kg * 16);
              bf16x8 bv = *(const bf16x8*)src;
              acc0 = __builtin_amdgcn_mfma_f32_16x16x32_bf16(a0, bv, acc0, 0, 0, 0);
              acc1 = __builtin_amdgcn_mfma_f32_16x16x32_bf16(a1, bv, acc1, 0, 0, 0);
            }
          }
        }
      }
    }
    int to = 2 * ut + et, xo = 2 * ux + ex, zo = 2 * uz + ez, yo = 2 * ln15 + ey;
    long opos = ((((long)b * 16 + to) * 32 + xo) * 32 + yo) * 16 + zo;
    short* dst = Xcl + opos * 40 + 20;
    {
      unsigned h[4];
#pragma unroll
      for (int r = 0; r < 4; r++) {
        float v = acc0[r] + bias[kg * 4 + r];
        v = (v >= 0.f) ? v : 0.1f * v;
        h[r] = (unsigned)(unsigned short)f2bf(v);
      }
      uint2 u;
      u.x = h[0] | (h[1] << 16);
      u.y = h[2] | (h[3] << 16);
      *(uint2*)(dst + kg * 4) = u;
    }
    if (kg == 0) {
      unsigned h[4];
#pragma unroll
      for (int r = 0; r < 4; r++) {
        float v = acc1[r] + bias[16 + r];
        v = (v >= 0.f) ? v : 0.1f * v;
        h[r] = (unsigned)(unsigned short)f2bf(v);
      }
      uint2 u;
      u.x = h[0] | (h[1] << 16);
      u.y = h[2] | (h[3] << 16);
      *(uint2*)(dst + 16) = u;
    }
  }
}

// ---------------- final conv: bf16 MFMA implicit GEMM ----------------
// XCD-aware swizzle: xcd = bid&7 selects (b, x-half) so x/t halo neighbors share an XCD L2.
// Register-cached B-frags: 6 distinct yi rows loaded once per (kt,kx,kz,ch), reused over ky.
__global__ __launch_bounds__(256) void k_fconv_mfma(
    const short* __restrict__ Xcl, const short* __restrict__ Wp,
    const short* __restrict__ zp, const float* __restrict__ bias,
    float* __restrict__ io) {
  int bid = blockIdx.x;
  int xcd = bid & 7, idx = bid >> 3;
  int b = xcd >> 1, xh = xcd & 1;
  int yb = idx & 1, t0 = (idx >> 1) & 15, x0 = xh * 16 + ((idx >> 5) & 15);
  int lane = threadIdx.x & 63, wave = threadIdx.x >> 6;
  int ln15 = lane & 15, kg = lane >> 4;
  int ybase = yb * 16 + wave * 4;

  f32x4 acc[2][4];
#pragma unroll
  for (int mt = 0; mt < 2; mt++)
#pragma unroll
    for (int nt = 0; nt < 4; nt++)
#pragma unroll
      for (int j = 0; j < 4; j++) acc[mt][nt][j] = 0.f;

  const char* xb = (const char*)Xcl;
  const char* wb = (const char*)Wp;
  const char* zb = (const char*)zp;

  for (int kt = 0; kt < 3; kt++) {
    int ti = t0 + kt - 1;
    if (ti < 0 || ti > 15) continue;
    for (int kx = 0; kx < 3; kx++) {
      int xi = x0 + kx - 1;
      if (xi < 0 || xi > 31) continue;
      long rowbase = ((long)((b * 16 + ti) * 32 + xi)) * 32;
#pragma unroll
      for (int kz = 0; kz < 3; kz++) {
        int zi = ln15 + kz - 1;
        bool zok = (zi >= 0) && (zi < 16);
#pragma unroll
        for (int ch = 0; ch < 2; ch++) {
          // 6 distinct B rows: yi = ybase-1 .. ybase+4
          bf16x8 bv[6];
#pragma unroll
          for (int j = 0; j < 6; j++) {
            int yi = ybase + j - 1;
            bool ok = zok && (yi >= 0) && (yi < 32);
            long pos = (rowbase + yi) * 16 + (long)zi;
            const char* src = ok ? (xb + pos * 80 + ch * 64 + kg * 16)
                                 : (zb + ch * 64 + kg * 16);
            bv[j] = *(const bf16x8*)src;
          }
          // 6 A frags: 3 ky x 2 mtiles
          bf16x8 av[3][2];
#pragma unroll
          for (int ky = 0; ky < 3; ky++) {
            int tap = ((kt * 3 + kx) * 3 + ky) * 3 + kz;
            const char* wt = wb + (size_t)tap * 4096 + ln15 * 128 + ch * 64 + kg * 16;
            av[ky][0] = *(const bf16x8*)wt;
            av[ky][1] = *(const bf16x8*)(wt + 2048);
          }
#pragma unroll
          for (int ky = 0; ky < 3; ky++)
#pragma unroll
            for (int nt = 0; nt < 4; nt++) {
              acc[0][nt] = __builtin_amdgcn_mfma_f32_16x16x32_bf16(av[ky][0], bv[nt + ky], acc[0][nt], 0, 0, 0);
              acc[1][nt] = __builtin_amdgcn_mfma_f32_16x16x32_bf16(av[ky][1], bv[nt + ky], acc[1][nt], 0, 0, 0);
            }
        }
      }
    }
  }

#pragma unroll
  for (int mt = 0; mt < 2; mt++)
#pragma unroll
    for (int r = 0; r < 4; r++) {
      int o = mt * 16 + kg * 4 + r;
      if (o >= 20) continue;
      float bo = bias[o];
#pragma unroll
      for (int nt = 0; nt < 4; nt++) {
        int y = ybase + nt;
        size_t oidx = ((size_t)(b * 20 + o)) * 262144 +
                      ((((size_t)t0 * 32 + x0) * 32 + y) * 16 + ln15);
        float v = acc[mt][nt][r] + bo + io[oidx];
        io[oidx] = fmaxf(v, 0.f);
      }
    }
}

extern "C" void kernel_launch(void* const* d_in, const int* in_sizes, int n_in,
                              void* d_out, int out_size, void* d_ws, size_t ws_size,
                              hipStream_t stream) {
  const float* x     = (const float*)d_in[0];
  const float* sw1   = (const float*)d_in[1];
  const float* sw2   = (const float*)d_in[2];
  const float* sw3   = (const float*)d_in[3];
  const float* sw4   = (const float*)d_in[4];
  const float* w_pw  = (const float*)d_in[5];
  const float* b_pw  = (const float*)d_in[6];
  const float* c1_w  = (const float*)d_in[7];
  const float* c2_w  = (const float*)d_in[8];
  const float* c21_w = (const float*)d_in[9];
  const float* c3_w  = (const float*)d_in[10];
  const float* c31_w = (const float*)d_in[11];
  const float* bn1_g = (const float*)d_in[12];
  const float* bn1_b = (const float*)d_in[13];
  const float* bn2_g = (const float*)d_in[14];
  const float* bn2_b = (const float*)d_in[15];
  const float* bn21_g = (const float*)d_in[16];
  const float* bn21_b = (const float*)d_in[17];
  const float* bn3_g = (const float*)d_in[18];
  const float* bn3_b = (const float*)d_in[19];
  const float* bn31_g = (const float*)d_in[20];
  const float* bn31_b = (const float*)d_in[21];
  const float* d2_w  = (const float*)d_in[22];
  const float* d2_b  = (const float*)d_in[23];
  const float* d1_w  = (const float*)d_in[24];
  const float* d1_b  = (const float*)d_in[25];
  const float* d0_w  = (const float*)d_in[26];
  const float* d0_b  = (const float*)d_in[27];
  const float* out_w = (const float*)d_in[28];
  const float* out_b = (const float*)d_in[29];
  float* out = (float*)d_out;
  float* ws = (float*)d_ws;

  // spectral arena (phase 1 only)
  float2* A  = (float2*)(ws);
  float2* Bb = (float2*)(ws + 10485760);
  float2* Cb = (float2*)(ws + 13107200);
  float2* Dd = (float2*)(ws + 14417920);
  float2* Ee = (float2*)(ws + 15073280);
  float2* Ff = (float2*)(ws + 15728640);
  float2* Gg = (float2*)(ws + 16384000);

  // U-Net arena
  float* oc1   = ws;
  short* CLd0  = (short*)(ws + 1310720);
  float* oc2a  = ws + 2621440;
  float* oc2   = ws + 2703360;
  float* oc3a  = ws + 2785280;
  float* oc3   = ws + 2790400;
  float* od2   = ws + 2795520;
  short* Xcl   = (short*)(ws + 2877440);
  float* stats = ws + 23848960;
  short* Wd = (short*)(ws);
  short* Wp = (short*)(ws + 262144);
  short* zp = (short*)(ws + 345088);

  auto nb = [](int n) { return (n + 255) / 256; };
  dim3 blk(256);

  // ---- spectral path: x1 -> d_out ----
  k_fwd_z<<<nb(1310720), blk, 0, stream>>>(x, A, 1310720);
  k_fwd_y<<<nb(1310720), blk, 0, stream>>>(A, Bb, 1310720);
  k_fwd_x<<<nb(655360), blk, 0, stream>>>(Bb, Cb, 655360);
  k_fwd_t<<<nb(327680), blk, 0, stream>>>(Cb, Dd, 327680);
  k_fwd_c<<<nb(327680), blk, 0, stream>>>(Dd, Ee, 327680);
  k_fwd_b<<<nb(327680), blk, 0, stream>>>(Ee, Ff, 327680);
  k_smul<<<nb(327680), blk, 0, stream>>>(Ff, sw1, sw2, sw3, sw4, Gg, 327680);
  k_inv_t<<<nb(655360), blk, 0, stream>>>(Gg, Cb, 655360);
  k_inv_x<<<nb(1310720), blk, 0, stream>>>(Cb, Bb, 1310720);
  k_inv_y<<<nb(5242880), blk, 0, stream>>>(Bb, A, 5242880);
  k_inv_z<<<nb(20971520), blk, 0, stream>>>(A, out, 20971520);

  // ---- pointwise path: += x2 ----
  k_x2<<<nb(1048576), blk, 0, stream>>>(x, w_pw, b_pw, out, 1048576);

  // ---- Xcl ci 0..19 from x ----
  k_xcl_x<<<nb(1048576), blk, 0, stream>>>(x, Xcl, 1048576);

  // ---- U-Net encoder ----
  k_conv4d_pos<<<nb(65536), blk, 0, stream>>>(x, 20, nullptr, 0, c1_w, oc1,
                                              16, 32, 32, 16, 8, 16, 16, 8, 2, 65536);
  k_bn_stats<<<20, blk, 0, stream>>>(oc1, 16384, stats);
  k_bn_apply_cl<<<nb(1310720), blk, 0, stream>>>(oc1, stats, bn1_g, bn1_b, CLd0, 1310720);

  k_conv4d_elem<<<nb(81920), blk, 0, stream>>>(oc1, c2_w, oc2a, 20,
                                               8, 16, 16, 8, 4, 8, 8, 4, 2, 81920);
  k_bn_stats<<<20, blk, 0, stream>>>(oc2a, 1024, stats);
  k_bn_apply<<<nb(81920), blk, 0, stream>>>(oc2a, 1024, stats, bn2_g, bn2_b, 81920);

  k_conv4d_elem<<<nb(81920), blk, 0, stream>>>(oc2a, c21_w, oc2, 20,
                                               4, 8, 8, 4, 4, 8, 8, 4, 1, 81920);
  k_bn_stats<<<20, blk, 0, stream>>>(oc2, 1024, stats);
  k_bn_apply<<<nb(81920), blk, 0, stream>>>(oc2, 1024, stats, bn21_g, bn21_b, 81920);

  k_conv4d_elem<<<nb(5120), blk, 0, stream>>>(oc2, c3_w, oc3a, 20,
                                              4, 8, 8, 4, 2, 4, 4, 2, 2, 5120);
  k_bn_stats<<<20, blk, 0, stream>>>(oc3a, 64, stats);
  k_bn_apply<<<nb(5120), blk, 0, stream>>>(oc3a, 64, stats, bn3_g, bn3_b, 5120);

  k_conv4d_elem<<<nb(5120), blk, 0, stream>>>(oc3a, c31_w, oc3, 20,
                                              2, 4, 4, 2, 2, 4, 4, 2, 1, 5120);
  k_bn_stats<<<20, blk, 0, stream>>>(oc3, 64, stats);
  k_bn_apply<<<nb(5120), blk, 0, stream>>>(oc3, 64, stats, bn31_g, bn31_b, 5120);

  // ---- decoder ----
  k_deconv4d<<<nb(4096), blk, 0, stream>>>(oc3, 20, nullptr, 0, d2_w, d2_b, od2,
                                           2, 4, 4, 2, 4096);
  k_deconv_d1_cl<<<nb(65536), blk, 0, stream>>>(oc2, od2, d1_w, d1_b, CLd0, 65536);

  // weight packs
  k_pack_w<<<nb(165888), blk, 0, stream>>>(out_w, Wp, zp, 165888);
  k_pack_wd<<<nb(524288), blk, 0, stream>>>(d0_w, Wd, 524288);

  // d0 deconv via MFMA -> Xcl ci 20..39
  k_d0_mfma<<<1024, blk, 0, stream>>>(CLd0, Wd, zp, d0_b, Xcl);

  // final conv via MFMA, fused +bias +x1+x2 +relu into d_out
  k_fconv_mfma<<<4096, blk, 0, stream>>>(Xcl, Wp, zp, out_b, out);
}

// Round 5
// 3408.730 us; speedup vs baseline: 2.7314x; 1.0184x over previous
//
#include <hip/hip_runtime.h>

#define PI2 6.28318530717958647692f

typedef __attribute__((ext_vector_type(8))) short bf16x8;
typedef __attribute__((ext_vector_type(4))) float f32x4;

__device__ __forceinline__ void cfma(float2& acc, float2 a, float2 t) {
  acc.x += a.x * t.x - a.y * t.y;
  acc.y += a.x * t.y + a.y * t.x;
}
// multiply by conj(t) (inverse twiddle), t = e^{-i\theta}
__device__ __forceinline__ void cfmac(float2& acc, float2 a, float2 t) {
  acc.x += a.x * t.x + a.y * t.y;
  acc.y += a.y * t.x - a.x * t.y;
}

__device__ __forceinline__ short f2bf(float f) {
  unsigned u = __float_as_uint(f);
  unsigned r = (u + 0x7fff + ((u >> 16) & 1)) >> 16;
  return (short)r;
}

// twiddle tables: T[0..31]=e^{-2pi i m/32}, T[32..47]=N16, T[48..67]=N20, T[68..71]=N4
__global__ void k_twid(float2* __restrict__ T) {
  int i = threadIdx.x;
  float s, c;
  if (i < 32) { __sincosf(-PI2 * (float)i / 32.f, &s, &c); T[i] = make_float2(c, s); }
  if (i < 16) { __sincosf(-PI2 * (float)i / 16.f, &s, &c); T[32 + i] = make_float2(c, s); }
  if (i < 20) { __sincosf(-PI2 * (float)i / 20.f, &s, &c); T[48 + i] = make_float2(c, s); }
  if (i < 4)  { __sincosf(-PI2 * (float)i / 4.f,  &s, &c); T[68 + i] = make_float2(c, s); }
}

// ---------------- spectral forward ----------------
__global__ void k_fwd_z(const float* __restrict__ x, const float2* __restrict__ T,
                        float2* __restrict__ out, int nrows) {
  __shared__ float2 tw[16];
  if (threadIdx.x < 16) tw[threadIdx.x] = T[32 + threadIdx.x];
  __syncthreads();
  int r = blockIdx.x * 256 + threadIdx.x;
  if (r >= nrows) return;
  const float* p = x + (size_t)r * 16;
  float v[16];
#pragma unroll
  for (int z = 0; z < 16; z++) v[z] = p[z];
#pragma unroll
  for (int zk = 0; zk < 4; zk++) {
    float re = 0.f, im = 0.f;
#pragma unroll
    for (int z = 0; z < 16; z++) {
      float2 t = tw[(z * zk) & 15];
      re += v[z] * t.x;
      im += v[z] * t.y;
    }
    out[(size_t)r * 4 + zk] = make_float2(re, im);
  }
}

__global__ void k_fwd_y(const float2* __restrict__ in, const float2* __restrict__ T,
                        float2* __restrict__ out, int n) {
  __shared__ float2 tw[32];
  if (threadIdx.x < 32) tw[threadIdx.x] = T[threadIdx.x];
  __syncthreads();
  int i = blockIdx.x * 256 + threadIdx.x;
  if (i >= n) return;
  int zk = i & 3, yk = (i >> 2) & 7, slab = i >> 5;
  const float2* p = in + (size_t)slab * 128 + zk;
  float2 acc = make_float2(0.f, 0.f);
  for (int y = 0; y < 32; y++) cfma(acc, p[y * 4], tw[(y * yk) & 31]);
  out[i] = acc;
}

__global__ void k_fwd_x(const float2* __restrict__ in, const float2* __restrict__ T,
                        float2* __restrict__ out, int n) {
  __shared__ float2 tw[32];
  if (threadIdx.x < 32) tw[threadIdx.x] = T[threadIdx.x];
  __syncthreads();
  int i = blockIdx.x * 256 + threadIdx.x;
  if (i >= n) return;
  int zk = i & 3, yk = (i >> 2) & 7, xi = (i >> 5) & 15, slab = i >> 9;
  int xk = (xi < 8) ? xi : xi + 16;
  const float2* p = in + (size_t)slab * 1024 + yk * 4 + zk;
  float2 acc = make_float2(0.f, 0.f);
  for (int xx = 0; xx < 32; xx++) cfma(acc, p[xx * 32], tw[(xx * xk) & 31]);
  out[i] = acc;
}

__global__ void k_fwd_t(const float2* __restrict__ in, const float2* __restrict__ T,
                        float2* __restrict__ out, int n) {
  __shared__ float2 tw[16];
  if (threadIdx.x < 16) tw[threadIdx.x] = T[32 + threadIdx.x];
  __syncthreads();
  int i = blockIdx.x * 256 + threadIdx.x;
  if (i >= n) return;
  int zk = i & 3, yk = (i >> 2) & 7, xi = (i >> 5) & 15, ti = (i >> 9) & 7, bc = i >> 12;
  int tk = (ti < 4) ? ti : ti + 8;
  const float2* p = in + (size_t)bc * 8192 + xi * 32 + yk * 4 + zk;
  float2 acc = make_float2(0.f, 0.f);
  for (int t = 0; t < 16; t++) cfma(acc, p[t * 512], tw[(t * tk) & 15]);
  out[i] = acc;
}

__global__ void k_fwd_c(const float2* __restrict__ in, const float2* __restrict__ T,
                        float2* __restrict__ out, int n) {
  __shared__ float2 tw[20];
  if (threadIdx.x < 20) tw[threadIdx.x] = T[48 + threadIdx.x];
  __syncthreads();
  int i = blockIdx.x * 256 + threadIdx.x;
  if (i >= n) return;
  int mode = i & 4095, r = i >> 12, ck = r % 20, b = r / 20;
  const float2* p = in + (size_t)b * 81920 + mode;
  float2 acc = make_float2(0.f, 0.f);
  int idx = 0;
  for (int c = 0; c < 20; c++) {
    cfma(acc, p[(size_t)c * 4096], tw[idx]);
    idx += ck; if (idx >= 20) idx -= 20;
  }
  out[i] = acc;
}

__global__ void k_fwd_b(const float2* __restrict__ in, const float2* __restrict__ T,
                        float2* __restrict__ out, int n) {
  __shared__ float2 tw[4];
  if (threadIdx.x < 4) tw[threadIdx.x] = T[68 + threadIdx.x];
  __syncthreads();
  int i = blockIdx.x * 256 + threadIdx.x;
  if (i >= n) return;
  int mode = i & 4095, r = i >> 12, ck = r % 20, bk = r / 20;
  const float2* p = in + (size_t)ck * 4096 + mode;
  float2 acc = make_float2(0.f, 0.f);
#pragma unroll
  for (int b = 0; b < 4; b++) cfma(acc, p[(size_t)b * 81920], tw[(b * bk) & 3]);
  out[i] = acc;
}

__global__ void k_smul(const float2* __restrict__ in,
                       const float* __restrict__ sw1, const float* __restrict__ sw2,
                       const float* __restrict__ sw3, const float* __restrict__ sw4,
                       float2* __restrict__ out, int n) {
  int i = blockIdx.x * 256 + threadIdx.x;
  if (i >= n) return;
  int mode = i & 4095, r = i >> 12, o = r % 20, bk = r / 20;
  int ti = mode >> 9, xi = (mode >> 5) & 15, yk = (mode >> 2) & 7, zk = mode & 3;
  const float* w = (ti < 4) ? ((xi < 8) ? sw1 : sw3) : ((xi < 8) ? sw2 : sw4);
  int tl = ti & 3, xl = xi & 7;
  const float2* wp = (const float2*)w;
  const float2* ip = in + (size_t)bk * 81920 + mode;
  size_t wsub = (size_t)o * 1024 + (size_t)tl * 256 + (size_t)xl * 32 + yk * 4 + zk;
  float2 acc = make_float2(0.f, 0.f);
  for (int ci = 0; ci < 20; ci++) cfma(acc, ip[(size_t)ci * 4096], wp[(size_t)ci * 20480 + wsub]);
  out[i] = acc;
}

// ---------------- spectral inverse ----------------
__global__ void k_inv_t(const float2* __restrict__ in, const float2* __restrict__ T,
                        float2* __restrict__ out, int n) {
  __shared__ float2 tw[16];
  if (threadIdx.x < 16) tw[threadIdx.x] = T[32 + threadIdx.x];
  __syncthreads();
  int i = blockIdx.x * 256 + threadIdx.x;
  if (i >= n) return;
  int zk = i & 3, yk = (i >> 2) & 7, xi = (i >> 5) & 15, tp = (i >> 9) & 15, bc = i >> 13;
  const float2* p = in + (size_t)bc * 4096 + xi * 32 + yk * 4 + zk;
  float2 acc = make_float2(0.f, 0.f);
#pragma unroll
  for (int ti = 0; ti < 8; ti++) {
    int tk = (ti < 4) ? ti : ti + 8;
    cfmac(acc, p[ti * 512], tw[(tk * tp) & 15]);
  }
  out[i] = acc;
}

__global__ void k_inv_x(const float2* __restrict__ in, const float2* __restrict__ T,
                        float2* __restrict__ out, int n) {
  __shared__ float2 tw[32];
  if (threadIdx.x < 32) tw[threadIdx.x] = T[threadIdx.x];
  __syncthreads();
  int i = blockIdx.x * 256 + threadIdx.x;
  if (i >= n) return;
  int zk = i & 3, yk = (i >> 2) & 7, xp = (i >> 5) & 31, tp = (i >> 10) & 15, bc = i >> 14;
  const float2* p = in + (size_t)bc * 8192 + tp * 512 + yk * 4 + zk;
  float2 acc = make_float2(0.f, 0.f);
#pragma unroll
  for (int xi = 0; xi < 16; xi++) {
    int xk = (xi < 8) ? xi : xi + 16;
    cfmac(acc, p[xi * 32], tw[(xk * xp) & 31]);
  }
  out[i] = acc;
}

// fused inverse-y + c2r-z: thread per (bc,tp,xp,yp), emits full 16-z real row.
__global__ void k_inv_yz(const float2* __restrict__ in, const float2* __restrict__ T,
                         float* __restrict__ out, int n) {
  __shared__ float2 tw[48];  // 0..31: N32, 32..47: N16
  if (threadIdx.x < 48) tw[threadIdx.x] = T[threadIdx.x];
  __syncthreads();
  int i = blockIdx.x * 256 + threadIdx.x;
  if (i >= n) return;
  int yp = i & 31;
  const float2* p = in + (size_t)(i >> 5) * 32;  // [bc][tp][xp] slab: [yk8][zk4]
  float2 Ay[4];
#pragma unroll
  for (int zk = 0; zk < 4; zk++) Ay[zk] = make_float2(0.f, 0.f);
#pragma unroll
  for (int yk = 0; yk < 8; yk++) {
    float2 w = tw[(yk * yp) & 31];
#pragma unroll
    for (int zk = 0; zk < 4; zk++) cfmac(Ay[zk], p[yk * 4 + zk], w);
  }
  float res[16];
#pragma unroll
  for (int zp = 0; zp < 16; zp++) {
    float v = Ay[0].x;
#pragma unroll
    for (int zk = 1; zk < 4; zk++) {
      float2 t = tw[32 + ((zk * zp) & 15)];
      v += 2.f * (Ay[zk].x * t.x + Ay[zk].y * t.y);
    }
    res[zp] = v * (1.f / 262144.f);
  }
  float4* o4 = (float4*)(out + (size_t)i * 16);
#pragma unroll
  for (int q = 0; q < 4; q++)
    o4[q] = make_float4(res[q * 4], res[q * 4 + 1], res[q * 4 + 2], res[q * 4 + 3]);
}

// ---------------- U-Net: convs ----------------
__global__ void k_conv4d_pos(const float* __restrict__ in1, int Ci1,
                             const float* __restrict__ in2, int Ci2,
                             const float* __restrict__ W, float* __restrict__ out,
                             int Ti, int Xi, int Yi, int Zi,
                             int To, int Xo, int Yo, int Zo, int stride, int n) {
  int idx = blockIdx.x * 256 + threadIdx.x;
  if (idx >= n) return;
  int zo = idx % Zo; int r = idx / Zo;
  int yo = r % Yo; r /= Yo;
  int xo = r % Xo; r /= Xo;
  int to = r % To; int b = r / To;
  float acc[20];
#pragma unroll
  for (int o = 0; o < 20; o++) acc[o] = 0.f;
  int Ci = Ci1 + Ci2;
  size_t in_sp = (size_t)Ti * Xi * Yi * Zi;
  for (int ci = 0; ci < Ci; ci++) {
    const float* base = (ci < Ci1) ? in1 + ((size_t)b * Ci1 + ci) * in_sp
                                   : in2 + ((size_t)b * Ci2 + (ci - Ci1)) * in_sp;
    const float* wc = W + (size_t)ci * 81;
    for (int kt = 0; kt < 3; kt++) {
      int t = to * stride + kt - 1; if (t < 0 || t >= Ti) continue;
      for (int kx = 0; kx < 3; kx++) {
        int xx = xo * stride + kx - 1; if (xx < 0 || xx >= Xi) continue;
        for (int ky = 0; ky < 3; ky++) {
          int y = yo * stride + ky - 1; if (y < 0 || y >= Yi) continue;
          for (int kz = 0; kz < 3; kz++) {
            int z = zo * stride + kz - 1; if (z < 0 || z >= Zi) continue;
            float v = base[(((size_t)t * Xi + xx) * Yi + y) * Zi + z];
            int tap = ((kt * 3 + kx) * 3 + ky) * 3 + kz;
#pragma unroll
            for (int o = 0; o < 20; o++) acc[o] += v * wc[(size_t)o * Ci * 81 + tap];
          }
        }
      }
    }
  }
  size_t osp = (size_t)To * Xo * Yo * Zo;
  size_t obase = (size_t)b * 20 * osp + (((size_t)to * Xo + xo) * Yo + yo) * Zo + zo;
#pragma unroll
  for (int o = 0; o < 20; o++) out[obase + (size_t)o * osp] = acc[o];
}

__global__ void k_conv4d_elem(const float* __restrict__ in, const float* __restrict__ W,
                              float* __restrict__ out, int Ci,
                              int Ti, int Xi, int Yi, int Zi,
                              int To, int Xo, int Yo, int Zo, int stride, int n) {
  int idx = blockIdx.x * 256 + threadIdx.x;
  if (idx >= n) return;
  int zo = idx % Zo; int r = idx / Zo;
  int yo = r % Yo; r /= Yo;
  int xo = r % Xo; r /= Xo;
  int to = r % To; r /= To;
  int o = r % 20; int b = r / 20;
  float acc = 0.f;
  size_t in_sp = (size_t)Ti * Xi * Yi * Zi;
  for (int ci = 0; ci < Ci; ci++) {
    const float* base = in + ((size_t)b * Ci + ci) * in_sp;
    const float* wc = W + ((size_t)o * Ci + ci) * 81;
    for (int kt = 0; kt < 3; kt++) {
      int t = to * stride + kt - 1; if (t < 0 || t >= Ti) continue;
      for (int kx = 0; kx < 3; kx++) {
        int xx = xo * stride + kx - 1; if (xx < 0 || xx >= Xi) continue;
        for (int ky = 0; ky < 3; ky++) {
          int y = yo * stride + ky - 1; if (y < 0 || y >= Yi) continue;
          for (int kz = 0; kz < 3; kz++) {
            int z = zo * stride + kz - 1; if (z < 0 || z >= Zi) continue;
            acc += base[(((size_t)t * Xi + xx) * Yi + y) * Zi + z] * wc[((kt * 3 + kx) * 3 + ky) * 3 + kz];
          }
        }
      }
    }
  }
  out[idx] = acc;
}

// ---------------- BN ----------------
__global__ void k_bn_stats(const float* __restrict__ d, int S, float* __restrict__ stats) {
  int c = blockIdx.x;
  int tid = threadIdx.x;
  float s = 0.f, s2 = 0.f;
  for (int b = 0; b < 4; b++) {
    const float* p = d + ((size_t)b * 20 + c) * S;
    for (int i = tid; i < S; i += 256) { float v = p[i]; s += v; s2 += v * v; }
  }
  __shared__ float ls[256], lq[256];
  ls[tid] = s; lq[tid] = s2;
  __syncthreads();
  for (int off = 128; off > 0; off >>= 1) {
    if (tid < off) { ls[tid] += ls[tid + off]; lq[tid] += lq[tid + off]; }
    __syncthreads();
  }
  if (tid == 0) {
    float cnt = 4.f * (float)S;
    float mean = ls[0] / cnt;
    float var = lq[0] / cnt - mean * mean;
    stats[2 * c] = mean;
    stats[2 * c + 1] = rsqrtf(var + 1e-5f);
  }
}

__global__ void k_bn_apply(float* __restrict__ d, int S, const float* __restrict__ stats,
                           const float* __restrict__ g, const float* __restrict__ bb, int n) {
  int idx = blockIdx.x * 256 + threadIdx.x;
  if (idx >= n) return;
  int c = (idx / S) % 20;
  float v = d[idx];
  v = (v - stats[2 * c]) * stats[2 * c + 1] * g[c] + bb[c];
  d[idx] = (v >= 0.f) ? v : 0.1f * v;
}

// BN apply for oc1 + bf16 channels-last copy into CLd0 ci 0..19
__global__ void k_bn_apply_cl(float* __restrict__ d, const float* __restrict__ stats,
                              const float* __restrict__ g, const float* __restrict__ bb,
                              short* __restrict__ CL, int n) {
  int idx = blockIdx.x * 256 + threadIdx.x;
  if (idx >= n) return;
  int s = idx & 16383;
  int r = idx >> 14;
  int c = r % 20, b = r / 20;
  float v = d[idx];
  v = (v - stats[2 * c]) * stats[2 * c + 1] * g[c] + bb[c];
  v = (v >= 0.f) ? v : 0.1f * v;
  d[idx] = v;
  CL[((size_t)(b * 16384 + s)) * 40 + c] = f2bf(v);
}

// ---------------- deconv (ConvTranspose4d k=4 s=2 p=1), bias+lrelu fused ----------------
__device__ __forceinline__ int dcands(int p, int n_in, int* q, int* k) {
  int cnt = 0;
  int q0 = (p + 1) >> 1, k0 = p + 1 - 2 * q0;
  if (q0 >= 0 && q0 < n_in) { q[cnt] = q0; k[cnt] = k0; cnt++; }
  int q1 = q0 - 1, k1 = k0 + 2;
  if (q1 >= 0 && q1 < n_in) { q[cnt] = q1; k[cnt] = k1; cnt++; }
  return cnt;
}

__global__ void k_deconv4d(const float* __restrict__ in1, int Ci1,
                           const float* __restrict__ in2, int Ci2,
                           const float* __restrict__ W, const float* __restrict__ bias,
                           float* __restrict__ out,
                           int Ti, int Xi, int Yi, int Zi, int n) {
  int idx = blockIdx.x * 256 + threadIdx.x;
  if (idx >= n) return;
  int To = 2 * Ti, Xo = 2 * Xi, Yo = 2 * Yi, Zo = 2 * Zi;
  int zo = idx % Zo; int r = idx / Zo;
  int yo = r % Yo; r /= Yo;
  int xo = r % Xo; r /= Xo;
  int to = r % To; int b = r / To;
  int qt[2], kt[2], qx[2], kx[2], qy[2], ky[2], qz[2], kz[2];
  int nt = dcands(to, Ti, qt, kt), nx = dcands(xo, Xi, qx, kx);
  int ny = dcands(yo, Yi, qy, ky), nz = dcands(zo, Zi, qz, kz);
  float acc[20];
#pragma unroll
  for (int o = 0; o < 20; o++) acc[o] = 0.f;
  int Ci = Ci1 + Ci2;
  size_t in_sp = (size_t)Ti * Xi * Yi * Zi;
  for (int ci = 0; ci < Ci; ci++) {
    const float* base = (ci < Ci1) ? in1 + ((size_t)b * Ci1 + ci) * in_sp
                                   : in2 + ((size_t)b * Ci2 + (ci - Ci1)) * in_sp;
    const float* wc = W + (size_t)ci * 5120;  // [ci][o(20)][256]
    for (int it = 0; it < nt; it++)
      for (int ix = 0; ix < nx; ix++)
        for (int iy = 0; iy < ny; iy++)
          for (int iz = 0; iz < nz; iz++) {
            float v = base[(((size_t)qt[it] * Xi + qx[ix]) * Yi + qy[iy]) * Zi + qz[iz]];
            int tap = ((kt[it] * 4 + kx[ix]) * 4 + ky[iy]) * 4 + kz[iz];
#pragma unroll
            for (int o = 0; o < 20; o++) acc[o] += v * wc[o * 256 + tap];
          }
  }
  size_t osp = (size_t)To * Xo * Yo * Zo;
  size_t obase = (size_t)b * 20 * osp + (((size_t)to * Xo + xo) * Yo + yo) * Zo + zo;
#pragma unroll
  for (int o = 0; o < 20; o++) {
    float v2 = acc[o] + bias[o];
    out[obase + (size_t)o * osp] = (v2 >= 0.f) ? v2 : 0.1f * v2;
  }
}

// d1 deconv: in 4x8x8x4 (oc2|od2, Ci=40) -> out 8x16x16x8 written bf16 CL ci 20..39
__global__ void k_deconv_d1_cl(const float* __restrict__ in1, const float* __restrict__ in2,
                               const float* __restrict__ W, const float* __restrict__ bias,
                               short* __restrict__ CL, int n) {
  int idx = blockIdx.x * 256 + threadIdx.x;
  if (idx >= n) return;
  int zo = idx & 7; int r = idx >> 3;
  int yo = r & 15; r >>= 4;
  int xo = r & 15; r >>= 4;
  int to = r & 7; int b = r >> 3;
  int qt[2], kt[2], qx[2], kx[2], qy[2], ky[2], qz[2], kz[2];
  int nt = dcands(to, 4, qt, kt), nx = dcands(xo, 8, qx, kx);
  int ny = dcands(yo, 8, qy, ky), nz = dcands(zo, 4, qz, kz);
  float acc[20];
#pragma unroll
  for (int o = 0; o < 20; o++) acc[o] = 0.f;
  const size_t in_sp = 4 * 8 * 8 * 4;
  for (int ci = 0; ci < 40; ci++) {
    const float* base = (ci < 20) ? in1 + ((size_t)b * 20 + ci) * in_sp
                                  : in2 + ((size_t)b * 20 + (ci - 20)) * in_sp;
    const float* wc = W + (size_t)ci * 5120;
    for (int it = 0; it < nt; it++)
      for (int ix = 0; ix < nx; ix++)
        for (int iy = 0; iy < ny; iy++)
          for (int iz = 0; iz < nz; iz++) {
            float v = base[(((size_t)qt[it] * 8 + qx[ix]) * 8 + qy[iy]) * 4 + qz[iz]];
            int tap = ((kt[it] * 4 + kx[ix]) * 4 + ky[iy]) * 4 + kz[iz];
#pragma unroll
            for (int o = 0; o < 20; o++) acc[o] += v * wc[o * 256 + tap];
          }
  }
  size_t pos = (((size_t)b * 8 + to) * 16 + xo) * 16 * 8 + (size_t)yo * 8 + zo;
  short* dst = CL + pos * 40 + 20;
#pragma unroll
  for (int o = 0; o < 20; o++) {
    float v2 = acc[o] + bias[o];
    v2 = (v2 >= 0.f) ? v2 : 0.1f * v2;
    dst[o] = f2bf(v2);
  }
}

// fill Xcl ci 0..19 from x
__global__ void k_xcl_x(const float* __restrict__ x, short* __restrict__ Xcl, int n) {
  int i = blockIdx.x * 256 + threadIdx.x;
  if (i >= n) return;
  int s = i & 262143, b = i >> 18;
  short* dst = Xcl + (size_t)i * 40;
  const float* src = x + (size_t)b * 20 * 262144 + s;
#pragma unroll
  for (int c = 0; c < 20; c++) dst[c] = f2bf(src[(size_t)c * 262144]);
}

// pack out_w [20][40][81] + w_pw [20][20] -> Wp[tap(82)][mt(2)][m(16)][k(64)] bf16 + zero-page
// tap 81 = pointwise (x2) weights.
__global__ void k_pack_w(const float* __restrict__ out_w, const float* __restrict__ w_pw,
                         short* __restrict__ Wp, short* __restrict__ zp, int n) {
  int i = blockIdx.x * 256 + threadIdx.x;
  if (i >= n) return;
  int k = i & 63, m = (i >> 6) & 15, mt = (i >> 10) & 1, tap = i >> 11;
  int o = mt * 16 + m;
  float v = 0.f;
  if (o < 20 && k < 40) {
    if (tap < 81) v = out_w[((size_t)o * 40 + k) * 81 + tap];
    else if (k < 20) v = w_pw[o * 20 + k];
  }
  Wp[i] = f2bf(v);
  if (i < 64) zp[i] = 0;
}

// pack d0_w [40][20][256] -> Wd[tap(256)][mt(2)][m(16)][k(64)] bf16
__global__ void k_pack_wd(const float* __restrict__ d0_w, short* __restrict__ Wd, int n) {
  int i = blockIdx.x * 256 + threadIdx.x;
  if (i >= n) return;
  int k = i & 63, m = (i >> 6) & 15, mt = (i >> 10) & 1, tap = i >> 11;
  int o = mt * 16 + m;
  float v = (o < 20 && k < 40) ? d0_w[((size_t)k * 20 + o) * 256 + tap] : 0.f;
  Wd[i] = f2bf(v);
}

// ---------------- d0 deconv via MFMA (parity-class decomposition) ----------------
__global__ __launch_bounds__(256) void k_d0_mfma(
    const short* __restrict__ CL, const short* __restrict__ Wd,
    const short* __restrict__ zp, const float* __restrict__ bias,
    short* __restrict__ Xcl) {
  int gw = blockIdx.x * 4 + (threadIdx.x >> 6);
  int uz = gw & 7, ux = (gw >> 3) & 15, ut = (gw >> 7) & 7, b = gw >> 10;
  int lane = threadIdx.x & 63;
  int ln15 = lane & 15, kg = lane >> 4;  // ln15 = uy

  const char* xb = (const char*)CL;
  const char* wb = (const char*)Wd;
  const char* zb = (const char*)zp;

#pragma unroll 1
  for (int cls = 0; cls < 16; cls++) {
    int et = (cls >> 3) & 1, ex = (cls >> 2) & 1, ey = (cls >> 1) & 1, ez = cls & 1;
    f32x4 acc0, acc1;
#pragma unroll
    for (int j = 0; j < 4; j++) { acc0[j] = 0.f; acc1[j] = 0.f; }
#pragma unroll
    for (int it = 0; it < 2; it++) {
      int kt = et ? (2 * it) : (1 + 2 * it);
      int qt = ut + (et ? (1 - it) : (-it));
      if (qt < 0 || qt > 7) continue;
#pragma unroll
      for (int ix = 0; ix < 2; ix++) {
        int kx = ex ? (2 * ix) : (1 + 2 * ix);
        int qx = ux + (ex ? (1 - ix) : (-ix));
        if (qx < 0 || qx > 15) continue;
#pragma unroll
        for (int iz = 0; iz < 2; iz++) {
          int kz = ez ? (2 * iz) : (1 + 2 * iz);
          int qz = uz + (ez ? (1 - iz) : (-iz));
          if (qz < 0 || qz > 7) continue;
#pragma unroll
          for (int iy = 0; iy < 2; iy++) {
            int ky = ey ? (2 * iy) : (1 + 2 * iy);
            int qy = ln15 + (ey ? (1 - iy) : (-iy));
            bool yok = (qy >= 0) && (qy < 16);
            int tap = ((kt * 4 + kx) * 4 + ky) * 4 + kz;
            long pos = ((((long)b * 8 + qt) * 16 + qx) * 16 + qy) * 8 + qz;
            const char* wt = wb + (size_t)tap * 4096;
#pragma unroll
            for (int ch = 0; ch < 2; ch++) {
              bf16x8 a0 = *(const bf16x8*)(wt + ln15 * 128 + ch * 64 + kg * 16);
              bf16x8 a1 = *(const bf16x8*)(wt + 2048 + ln15 * 128 + ch * 64 + kg * 16);
              const char* src = yok ? (xb + pos * 80 + ch * 64 + kg * 16)
                                    : (zb + ch * 64 + kg * 16);
              bf16x8 bv = *(const bf16x8*)src;
              acc0 = __builtin_amdgcn_mfma_f32_16x16x32_bf16(a0, bv, acc0, 0, 0, 0);
              acc1 = __builtin_amdgcn_mfma_f32_16x16x32_bf16(a1, bv, acc1, 0, 0, 0);
            }
          }
        }
      }
    }
    int to = 2 * ut + et, xo = 2 * ux + ex, zo = 2 * uz + ez, yo = 2 * ln15 + ey;
    long opos = ((((long)b * 16 + to) * 32 + xo) * 32 + yo) * 16 + zo;
    short* dst = Xcl + opos * 40 + 20;
    {
      unsigned h[4];
#pragma unroll
      for (int r = 0; r < 4; r++) {
        float v = acc0[r] + bias[kg * 4 + r];
        v = (v >= 0.f) ? v : 0.1f * v;
        h[r] = (unsigned)(unsigned short)f2bf(v);
      }
      uint2 u;
      u.x = h[0] | (h[1] << 16);
      u.y = h[2] | (h[3] << 16);
      *(uint2*)(dst + kg * 4) = u;
    }
    if (kg == 0) {
      unsigned h[4];
#pragma unroll
      for (int r = 0; r < 4; r++) {
        float v = acc1[r] + bias[16 + r];
        v = (v >= 0.f) ? v : 0.1f * v;
        h[r] = (unsigned)(unsigned short)f2bf(v);
      }
      uint2 u;
      u.x = h[0] | (h[1] << 16);
      u.y = h[2] | (h[3] << 16);
      *(uint2*)(dst + 16) = u;
    }
  }
}

// ---------------- final conv: bf16 MFMA implicit GEMM (+ fused pointwise x2 tap) ----------------
__global__ __launch_bounds__(256) void k_fconv_mfma(
    const short* __restrict__ Xcl, const short* __restrict__ Wp,
    const short* __restrict__ zp, const float* __restrict__ bias,
    const float* __restrict__ bpw, float* __restrict__ io) {
  int bid = blockIdx.x;
  int xcd = bid & 7, idx = bid >> 3;
  int b = xcd >> 1, xh = xcd & 1;
  int yb = idx & 1, t0 = (idx >> 1) & 15, x0 = xh * 16 + ((idx >> 5) & 15);
  int lane = threadIdx.x & 63, wave = threadIdx.x >> 6;
  int ln15 = lane & 15, kg = lane >> 4;
  int ybase = yb * 16 + wave * 4;

  f32x4 acc[2][4];
#pragma unroll
  for (int mt = 0; mt < 2; mt++)
#pragma unroll
    for (int nt = 0; nt < 4; nt++)
#pragma unroll
      for (int j = 0; j < 4; j++) acc[mt][nt][j] = 0.f;

  const char* xb = (const char*)Xcl;
  const char* wb = (const char*)Wp;
  const char* zb = (const char*)zp;

  for (int kt = 0; kt < 3; kt++) {
    int ti = t0 + kt - 1;
    if (ti < 0 || ti > 15) continue;
    for (int kx = 0; kx < 3; kx++) {
      int xi = x0 + kx - 1;
      if (xi < 0 || xi > 31) continue;
      long rowbase = ((long)((b * 16 + ti) * 32 + xi)) * 32;
#pragma unroll
      for (int kz = 0; kz < 3; kz++) {
        int zi = ln15 + kz - 1;
        bool zok = (zi >= 0) && (zi < 16);
#pragma unroll
        for (int ch = 0; ch < 2; ch++) {
          bf16x8 bv[6];
#pragma unroll
          for (int j = 0; j < 6; j++) {
            int yi = ybase + j - 1;
            bool ok = zok && (yi >= 0) && (yi < 32);
            long pos = (rowbase + yi) * 16 + (long)zi;
            const char* src = ok ? (xb + pos * 80 + ch * 64 + kg * 16)
                                 : (zb + ch * 64 + kg * 16);
            bv[j] = *(const bf16x8*)src;
          }
          bf16x8 av[3][2];
#pragma unroll
          for (int ky = 0; ky < 3; ky++) {
            int tap = ((kt * 3 + kx) * 3 + ky) * 3 + kz;
            const char* wt = wb + (size_t)tap * 4096 + ln15 * 128 + ch * 64 + kg * 16;
            av[ky][0] = *(const bf16x8*)wt;
            av[ky][1] = *(const bf16x8*)(wt + 2048);
          }
#pragma unroll
          for (int ky = 0; ky < 3; ky++)
#pragma unroll
            for (int nt = 0; nt < 4; nt++) {
              acc[0][nt] = __builtin_amdgcn_mfma_f32_16x16x32_bf16(av[ky][0], bv[nt + ky], acc[0][nt], 0, 0, 0);
              acc[1][nt] = __builtin_amdgcn_mfma_f32_16x16x32_bf16(av[ky][1], bv[nt + ky], acc[1][nt], 0, 0, 0);
            }
        }
      }
    }
  }

  // fused pointwise (x2) tap: ci 0..19 only (ch=0; weights for ci>=20 are zero)
  {
    long rowbase = ((long)((b * 16 + t0) * 32 + x0)) * 32;
    const char* wt = wb + (size_t)81 * 4096 + ln15 * 128 + kg * 16;
    bf16x8 a0 = *(const bf16x8*)wt;
    bf16x8 a1 = *(const bf16x8*)(wt + 2048);
#pragma unroll
    for (int nt = 0; nt < 4; nt++) {
      int yi = ybase + nt;
      long pos = (rowbase + yi) * 16 + (long)ln15;
      bf16x8 bv = *(const bf16x8*)(xb + pos * 80 + kg * 16);
      acc[0][nt] = __builtin_amdgcn_mfma_f32_16x16x32_bf16(a0, bv, acc[0][nt], 0, 0, 0);
      acc[1][nt] = __builtin_amdgcn_mfma_f32_16x16x32_bf16(a1, bv, acc[1][nt], 0, 0, 0);
    }
  }

#pragma unroll
  for (int mt = 0; mt < 2; mt++)
#pragma unroll
    for (int r = 0; r < 4; r++) {
      int o = mt * 16 + kg * 4 + r;
      if (o >= 20) continue;
      float bo = bias[o] + bpw[o];
#pragma unroll
      for (int nt = 0; nt < 4; nt++) {
        int y = ybase + nt;
        size_t oidx = ((size_t)(b * 20 + o)) * 262144 +
                      ((((size_t)t0 * 32 + x0) * 32 + y) * 16 + ln15);
        float v = acc[mt][nt][r] + bo + io[oidx];
        io[oidx] = fmaxf(v, 0.f);
      }
    }
}

extern "C" void kernel_launch(void* const* d_in, const int* in_sizes, int n_in,
                              void* d_out, int out_size, void* d_ws, size_t ws_size,
                              hipStream_t stream) {
  const float* x     = (const float*)d_in[0];
  const float* sw1   = (const float*)d_in[1];
  const float* sw2   = (const float*)d_in[2];
  const float* sw3   = (const float*)d_in[3];
  const float* sw4   = (const float*)d_in[4];
  const float* w_pw  = (const float*)d_in[5];
  const float* b_pw  = (const float*)d_in[6];
  const float* c1_w  = (const float*)d_in[7];
  const float* c2_w  = (const float*)d_in[8];
  const float* c21_w = (const float*)d_in[9];
  const float* c3_w  = (const float*)d_in[10];
  const float* c31_w = (const float*)d_in[11];
  const float* bn1_g = (const float*)d_in[12];
  const float* bn1_b = (const float*)d_in[13];
  const float* bn2_g = (const float*)d_in[14];
  const float* bn2_b = (const float*)d_in[15];
  const float* bn21_g = (const float*)d_in[16];
  const float* bn21_b = (const float*)d_in[17];
  const float* bn3_g = (const float*)d_in[18];
  const float* bn3_b = (const float*)d_in[19];
  const float* bn31_g = (const float*)d_in[20];
  const float* bn31_b = (const float*)d_in[21];
  const float* d2_w  = (const float*)d_in[22];
  const float* d2_b  = (const float*)d_in[23];
  const float* d1_w  = (const float*)d_in[24];
  const float* d1_b  = (const float*)d_in[25];
  const float* d0_w  = (const float*)d_in[26];
  const float* d0_b  = (const float*)d_in[27];
  const float* out_w = (const float*)d_in[28];
  const float* out_b = (const float*)d_in[29];
  float* out = (float*)d_out;
  float* ws = (float*)d_ws;

  // spectral arena (phase 1 only)
  float2* A  = (float2*)(ws);
  float2* Bb = (float2*)(ws + 10485760);
  float2* Cb = (float2*)(ws + 13107200);
  float2* Dd = (float2*)(ws + 14417920);
  float2* Ee = (float2*)(ws + 15073280);
  float2* Ff = (float2*)(ws + 15728640);
  float2* Gg = (float2*)(ws + 16384000);
  // twiddle tables: live only during spectral phase; region inside Xcl span,
  // beyond the spectral arena end (17,039,360 fl), overwritten later by k_xcl_x.
  float2* Twid = (float2*)(ws + 23000000);

  // U-Net arena
  float* oc1   = ws;
  short* CLd0  = (short*)(ws + 1310720);
  float* oc2a  = ws + 2621440;
  float* oc2   = ws + 2703360;
  float* oc3a  = ws + 2785280;
  float* oc3   = ws + 2790400;
  float* od2   = ws + 2795520;
  short* Xcl   = (short*)(ws + 2877440);
  float* stats = ws + 23848960;
  short* Wd = (short*)(ws);
  short* Wp = (short*)(ws + 262144);
  short* zp = (short*)(ws + 349184);

  auto nb = [](int n) { return (n + 255) / 256; };
  dim3 blk(256);

  // ---- twiddle tables ----
  k_twid<<<1, 64, 0, stream>>>(Twid);

  // ---- spectral path: x1 -> d_out ----
  k_fwd_z<<<nb(1310720), blk, 0, stream>>>(x, Twid, A, 1310720);
  k_fwd_y<<<nb(1310720), blk, 0, stream>>>(A, Twid, Bb, 1310720);
  k_fwd_x<<<nb(655360), blk, 0, stream>>>(Bb, Twid, Cb, 655360);
  k_fwd_t<<<nb(327680), blk, 0, stream>>>(Cb, Twid, Dd, 327680);
  k_fwd_c<<<nb(327680), blk, 0, stream>>>(Dd, Twid, Ee, 327680);
  k_fwd_b<<<nb(327680), blk, 0, stream>>>(Ee, Twid, Ff, 327680);
  k_smul<<<nb(327680), blk, 0, stream>>>(Ff, sw1, sw2, sw3, sw4, Gg, 327680);
  k_inv_t<<<nb(655360), blk, 0, stream>>>(Gg, Twid, Cb, 655360);
  k_inv_x<<<nb(1310720), blk, 0, stream>>>(Cb, Twid, Bb, 1310720);
  k_inv_yz<<<nb(1310720), blk, 0, stream>>>(Bb, Twid, out, 1310720);

  // ---- Xcl ci 0..19 from x ----
  k_xcl_x<<<nb(1048576), blk, 0, stream>>>(x, Xcl, 1048576);

  // ---- U-Net encoder ----
  k_conv4d_pos<<<nb(65536), blk, 0, stream>>>(x, 20, nullptr, 0, c1_w, oc1,
                                              16, 32, 32, 16, 8, 16, 16, 8, 2, 65536);
  k_bn_stats<<<20, blk, 0, stream>>>(oc1, 16384, stats);
  k_bn_apply_cl<<<nb(1310720), blk, 0, stream>>>(oc1, stats, bn1_g, bn1_b, CLd0, 1310720);

  k_conv4d_elem<<<nb(81920), blk, 0, stream>>>(oc1, c2_w, oc2a, 20,
                                               8, 16, 16, 8, 4, 8, 8, 4, 2, 81920);
  k_bn_stats<<<20, blk, 0, stream>>>(oc2a, 1024, stats);
  k_bn_apply<<<nb(81920), blk, 0, stream>>>(oc2a, 1024, stats, bn2_g, bn2_b, 81920);

  k_conv4d_elem<<<nb(81920), blk, 0, stream>>>(oc2a, c21_w, oc2, 20,
                                               4, 8, 8, 4, 4, 8, 8, 4, 1, 81920);
  k_bn_stats<<<20, blk, 0, stream>>>(oc2, 1024, stats);
  k_bn_apply<<<nb(81920), blk, 0, stream>>>(oc2, 1024, stats, bn21_g, bn21_b, 81920);

  k_conv4d_elem<<<nb(5120), blk, 0, stream>>>(oc2, c3_w, oc3a, 20,
                                              4, 8, 8, 4, 2, 4, 4, 2, 2, 5120);
  k_bn_stats<<<20, blk, 0, stream>>>(oc3a, 64, stats);
  k_bn_apply<<<nb(5120), blk, 0, stream>>>(oc3a, 64, stats, bn3_g, bn3_b, 5120);

  k_conv4d_elem<<<nb(5120), blk, 0, stream>>>(oc3a, c31_w, oc3, 20,
                                              2, 4, 4, 2, 2, 4, 4, 2, 1, 5120);
  k_bn_stats<<<20, blk, 0, stream>>>(oc3, 64, stats);
  k_bn_apply<<<nb(5120), blk, 0, stream>>>(oc3, 64, stats, bn31_g, bn31_b, 5120);

  // ---- decoder ----
  k_deconv4d<<<nb(4096), blk, 0, stream>>>(oc3, 20, nullptr, 0, d2_w, d2_b, od2,
                                           2, 4, 4, 2, 4096);
  k_deconv_d1_cl<<<nb(65536), blk, 0, stream>>>(oc2, od2, d1_w, d1_b, CLd0, 65536);

  // weight packs
  k_pack_w<<<nb(167936), blk, 0, stream>>>(out_w, w_pw, Wp, zp, 167936);
  k_pack_wd<<<nb(524288), blk, 0, stream>>>(d0_w, Wd, 524288);

  // d0 deconv via MFMA -> Xcl ci 20..39
  k_d0_mfma<<<1024, blk, 0, stream>>>(CLd0, Wd, zp, d0_b, Xcl);

  // final conv via MFMA, fused +bias +x1 +x2(pointwise tap) +relu into d_out
  k_fconv_mfma<<<4096, blk, 0, stream>>>(Xcl, Wp, zp, out_b, b_pw, out);
}